// Round 5
// baseline (914.689 us; speedup 1.0000x reference)
//
#include <hip/hip_runtime.h>
#include <hip/hip_bf16.h>

#define NSLOT 8
#define SDIM 256
#define FDIM 128
#define NHEAD 4
#define HDIM 64
#define NPOS 4096

__device__ __forceinline__ float bf2f(__hip_bfloat16 x) { return __bfloat162float(x); }

// ---------------- Kernel 1: LN(slots) @ Wq + bq -> q (f32, stashed in d_out),
// and zero the agg accumulator in d_ws. All f32.
__global__ __launch_bounds__(256) void k_prep(
    const float* __restrict__ slots,
    const float* __restrict__ Wq, const float* __restrict__ bq,
    const float* __restrict__ g_pre, const float* __restrict__ b_pre,
    float* __restrict__ q_out, float* __restrict__ agg_ws)
{
    int row = blockIdx.x;            // b*8 + s
    int t = threadIdx.x;
    __shared__ float s_ln[SDIM];
    __shared__ float r1[256], r2[256];

    float x = slots[row * SDIM + t];
    r1[t] = x; r2[t] = x * x;
    agg_ws[row * SDIM + t] = 0.0f;   // zero agg accumulator (ws is poisoned 0xAA)
    __syncthreads();
    for (int o = 128; o > 0; o >>= 1) {
        if (t < o) { r1[t] += r1[t + o]; r2[t] += r2[t + o]; }
        __syncthreads();
    }
    float mu  = r1[0] * (1.0f / SDIM);
    float var = r2[0] * (1.0f / SDIM) - mu * mu;
    float ln = (x - mu) * rsqrtf(var + 1e-5f) * g_pre[t] + b_pre[t];
    s_ln[t] = ln;
    __syncthreads();

    float acc = bq[t];
    for (int k = 0; k < SDIM; k++) acc += s_ln[k] * Wq[k * SDIM + t];
    int b = row >> 3, s = row & 7, h = t >> 6, d = t & 63;
    q_out[((b * NHEAD + h) * NSLOT + s) * HDIM + d] = acc;   // layout [b][h][s][d]
}

// ---------------- Kernel 2: fused kv-proj + scores + softmax(slots) + agg --
// LDS: s_q 8KB + s_agg 8KB + s_attn 4KB + s_u 16KB = 36KB.
// s_u holds the f32 feats tile [c][p] (128x32), then is REUSED (after sync)
// as bf16 k-tile [p][256] (16KB exactly). v stays in registers: the agg step
// for thread t consumes exactly v[p][t], which thread t itself computed.
__global__ __launch_bounds__(256) void k_attn(
    const float* __restrict__ feat,   // (B,128,4096)
    const float* __restrict__ Wk, const float* __restrict__ bk,
    const float* __restrict__ Wv, const float* __restrict__ bv,
    const float* __restrict__ q_in,   // f32 q stash (= d_out), [b][h][s][d]
    float* __restrict__ agg_ws)
{
    int t = threadIdx.x;
    int b = blockIdx.y;
    int n0 = blockIdx.x * 128;       // this block covers 128 positions (4 tiles of 32)

    __shared__ float s_q[2048];      // q for this batch: [h][s][d]
    __shared__ float s_agg[2048];    // [s][d] accumulator
    __shared__ float s_attn[1024];   // [p][h*8+s]
    __shared__ __align__(16) float s_u[4096];  // feats f32 [c][p=32]; later k bf16 [p][256]
    __hip_bfloat16* s_k = (__hip_bfloat16*)s_u;

    for (int i = 0; i < 8; i++) {
        s_q[i * 256 + t] = q_in[b * 2048 + i * 256 + t];
        s_agg[i * 256 + t] = 0.0f;
    }
    float bkt = bk[t], bvt = bv[t];

    for (int tt = 0; tt < 4; ++tt) {
        __syncthreads();             // protect s_u/s_attn from previous-iter readers
        int nb = n0 + tt * 32;
        // stage feats tile (128 ch x 32 pos), coalesced along positions
        for (int i = 0; i < 16; i++) {
            int idx = i * 256 + t;
            int c = idx >> 5, p = idx & 31;
            s_u[c * 32 + p] = feat[(size_t)b * (FDIM * NPOS) + (size_t)c * NPOS + nb + p];
        }
        __syncthreads();

        // kv: thread t owns k-column t and v-column t, for all 32 positions
        float ak[32], av[32];
        #pragma unroll
        for (int p = 0; p < 32; p++) { ak[p] = 0.0f; av[p] = 0.0f; }
        for (int c = 0; c < FDIM; c++) {
            float wk = Wk[c * SDIM + t];
            float wv = Wv[c * SDIM + t];
            const float4* f4 = (const float4*)&s_u[c * 32];  // uniform-address broadcast
            #pragma unroll
            for (int pb = 0; pb < 8; pb++) {
                float4 f = f4[pb];
                ak[pb*4+0] += f.x * wk; ak[pb*4+1] += f.y * wk;
                ak[pb*4+2] += f.z * wk; ak[pb*4+3] += f.w * wk;
                av[pb*4+0] += f.x * wv; av[pb*4+1] += f.y * wv;
                av[pb*4+2] += f.z * wv; av[pb*4+3] += f.w * wv;
            }
        }
        __syncthreads();             // all feats reads done before aliasing s_u as s_k
        #pragma unroll
        for (int p = 0; p < 32; p++)
            s_k[p * 256 + t] = __float2bfloat16(ak[p] + bkt);   // 32*256 bf16 = 16KB
        __syncthreads();

        // scores: 32 pos x (4 heads x 8 slots), each a 64-dot
        for (int i = 0; i < 4; i++) {
            int idx = i * 256 + t;
            int p = idx >> 5, hs = idx & 31;
            int h = hs >> 3;
            const float* qq = &s_q[hs * 64];
            const __hip_bfloat16* kp = &s_k[p * 256 + h * 64];
            float acc = 0.0f;
            for (int d = 0; d < 64; d++) acc += qq[d] * bf2f(kp[d]);
            s_attn[p * 32 + hs] = acc * 0.125f;   // scale = 64^-0.5
        }
        __syncthreads();

        // softmax over the 8 slots, per (p, h)
        if (t < 128) {
            int p = t >> 2, h = t & 3;
            float* a = &s_attn[p * 32 + h * 8];
            float m = a[0];
            for (int s = 1; s < 8; s++) m = fmaxf(m, a[s]);
            float e[8], sum = 0.0f;
            for (int s = 0; s < 8; s++) { e[s] = __expf(a[s] - m); sum += e[s]; }
            float inv = 1.0f / sum;
            for (int s = 0; s < 8; s++) a[s] = e[s] * inv;
        }
        __syncthreads();

        // agg: thread t owns output dim d=t (head h = t/64); v[p][t] = av[p]+bvt
        {
            int h = t >> 6;
            float accs[8];
            #pragma unroll
            for (int s = 0; s < 8; s++) accs[s] = 0.0f;
            for (int p = 0; p < 32; p++) {
                float vp = av[p] + bvt;
                const float* ap = &s_attn[p * 32 + h * 8];
                #pragma unroll
                for (int s = 0; s < 8; s++) accs[s] += ap[s] * vp;
            }
            #pragma unroll
            for (int s = 0; s < 8; s++) s_agg[s * 256 + t] += accs[s];
        }
    }
    __syncthreads();
    for (int i = 0; i < 8; i++)
        atomicAdd(&agg_ws[b * 2048 + i * 256 + t], s_agg[i * 256 + t]);
}

// ---------------- Kernel 3: GRU cell + post-LN + MLP + residual ------------
__global__ __launch_bounds__(256) void k_gru(
    const float* __restrict__ slots,
    const float* __restrict__ W_ih, const float* __restrict__ b_ih,
    const float* __restrict__ W_hh, const float* __restrict__ b_hh,
    const float* __restrict__ g_post, const float* __restrict__ b_post,
    const float* __restrict__ W1, const float* __restrict__ b1,
    const float* __restrict__ W2, const float* __restrict__ b2,
    const float* __restrict__ agg_ws, float* __restrict__ out)
{
    int row = blockIdx.x, t = threadIdx.x;   // row = b*8 + s
    __shared__ float s_x[256], s_h[256], s_ln[256], s_y1[512];
    __shared__ float r1[256], r2[256];

    float xv = agg_ws[row * 256 + t];
    float hv = slots[row * 256 + t];
    s_x[t] = xv; s_h[t] = hv;
    __syncthreads();

    // gates: thread t computes gi/gh for j = t (r), 256+t (z), 512+t (n)
    float gi[3], gh[3];
    for (int g = 0; g < 3; g++) {
        int j = g * 256 + t;
        float a1 = b_ih[j], a2 = b_hh[j];
        const float* wi = W_ih + (size_t)j * 256;
        const float* wh = W_hh + (size_t)j * 256;
        for (int k = 0; k < 256; k++) {
            a1 += s_x[k] * wi[k];
            a2 += s_h[k] * wh[k];
        }
        gi[g] = a1; gh[g] = a2;
    }
    float r  = 1.0f / (1.0f + __expf(-(gi[0] + gh[0])));
    float z  = 1.0f / (1.0f + __expf(-(gi[1] + gh[1])));
    float nn = tanhf(gi[2] + r * gh[2]);
    float hnew = (1.0f - z) * nn + z * hv;

    // post-LayerNorm over the 256-dim row (LDS tree)
    r1[t] = hnew; r2[t] = hnew * hnew;
    __syncthreads();
    for (int o = 128; o > 0; o >>= 1) {
        if (t < o) { r1[t] += r1[t + o]; r2[t] += r2[t + o]; }
        __syncthreads();
    }
    float mu  = r1[0] * (1.0f / 256);
    float var = r2[0] * (1.0f / 256) - mu * mu;
    float ln = (hnew - mu) * rsqrtf(var + 1e-5f) * g_post[t] + b_post[t];
    s_ln[t] = ln;
    __syncthreads();

    // MLP layer 1: (256) @ W1(256,512), relu
    for (int i = 0; i < 2; i++) {
        int j = i * 256 + t;
        float a = b1[j];
        for (int k = 0; k < 256; k++) a += s_ln[k] * W1[k * 512 + j];
        s_y1[j] = fmaxf(a, 0.0f);
    }
    __syncthreads();

    // MLP layer 2 + residual
    float o = hnew + b2[t];
    for (int j = 0; j < 512; j++) o += s_y1[j] * W2[j * 256 + t];
    out[row * 256 + t] = o;
}

extern "C" void kernel_launch(void* const* d_in, const int* in_sizes, int n_in,
                              void* d_out, int out_size, void* d_ws, size_t ws_size,
                              hipStream_t stream) {
    const float* features = (const float*)d_in[0];
    const float* slots    = (const float*)d_in[1];
    const float* Wq   = (const float*)d_in[2];
    const float* bq   = (const float*)d_in[3];
    const float* Wk   = (const float*)d_in[4];
    const float* bk   = (const float*)d_in[5];
    const float* Wv   = (const float*)d_in[6];
    const float* bv   = (const float*)d_in[7];
    const float* W_ih = (const float*)d_in[8];
    const float* b_ih = (const float*)d_in[9];
    const float* W_hh = (const float*)d_in[10];
    const float* b_hh = (const float*)d_in[11];
    const float* g_pre  = (const float*)d_in[12];
    const float* b_pre  = (const float*)d_in[13];
    const float* g_post = (const float*)d_in[14];
    const float* b_post = (const float*)d_in[15];
    const float* W1 = (const float*)d_in[16];
    const float* b1 = (const float*)d_in[17];
    const float* W2 = (const float*)d_in[18];
    const float* b2 = (const float*)d_in[19];
    float* out = (float*)d_out;

    // q (f32) is stashed in d_out itself: exactly 65536 floats, then fully
    // overwritten by k_gru. d_ws holds only the 256KB f32 agg accumulator.
    float* agg_ws = (float*)d_ws;          // 65536 f32: agg[b][s][d]

    k_prep<<<dim3(256), dim3(256), 0, stream>>>(slots, Wq, bq, g_pre, b_pre, out, agg_ws);
    k_attn<<<dim3(32, 32), dim3(256), 0, stream>>>(features, Wk, bk, Wv, bv, out, agg_ws);
    k_gru<<<dim3(256), dim3(256), 0, stream>>>(slots, W_ih, b_ih, W_hh, b_hh,
                                               g_post, b_post, W1, b1, W2, b2, agg_ws, out);
}

// Round 6
// 418.309 us; speedup vs baseline: 2.1866x; 2.1866x over previous
//
#include <hip/hip_runtime.h>
#include <hip/hip_bf16.h>

#define NSLOT 8
#define SDIM 256
#define FDIM 128
#define NHEAD 4
#define HDIM 64
#define NPOS 4096

__device__ __forceinline__ float bf2f(__hip_bfloat16 x) { return __bfloat162float(x); }

// ---------------- Kernel 1 (per batch): LN(slots), q = LN@Wq+bq, then
// qk[c][hs] = sum_d Wk[c][h*64+d] * q[s][h*64+d]  (k-projection folded into q!)
// qb[hs]   = sum_d bk[h*64+d]    * q[s][h*64+d]
// Also zeroes this batch's agg slice (which lives in d_out).
__global__ __launch_bounds__(256) void k_prep(
    const float* __restrict__ slots,
    const float* __restrict__ Wq, const float* __restrict__ bq,
    const float* __restrict__ g_pre, const float* __restrict__ b_pre,
    const float* __restrict__ Wk, const float* __restrict__ bk,
    float* __restrict__ qk_ws, float* __restrict__ qb_ws,
    float* __restrict__ agg_ws)
{
    int b = blockIdx.x, t = threadIdx.x;
    __shared__ float s_ln[8 * 256];
    __shared__ float q_l[32 * 65];     // [(s*4+h)*65 + d] — stride 65: conflict-free
    __shared__ float red1[256], red2[256];

    for (int i = 0; i < 8; i++) agg_ws[b * 2048 + i * 256 + t] = 0.0f;

    // LN: thread t -> row s8 = t>>5, covers 8 elements
    int s8 = t >> 5, lane = t & 31;
    float xv[8], sum = 0.0f, sq = 0.0f;
    for (int u = 0; u < 8; u++) {
        float x = slots[(b * 8 + s8) * 256 + lane * 8 + u];
        xv[u] = x; sum += x; sq += x * x;
    }
    red1[t] = sum; red2[t] = sq;
    __syncthreads();
    for (int o = 16; o > 0; o >>= 1) {
        if (lane < o) { red1[t] += red1[t + o]; red2[t] += red2[t + o]; }
        __syncthreads();
    }
    float mu  = red1[s8 * 32] * (1.0f / 256);
    float var = red2[s8 * 32] * (1.0f / 256) - mu * mu;
    float rstd = rsqrtf(var + 1e-5f);
    for (int u = 0; u < 8; u++) {
        int j = lane * 8 + u;
        s_ln[s8 * 256 + j] = (xv[u] - mu) * rstd * g_pre[j] + b_pre[j];
    }
    __syncthreads();

    // q[s][t] = sum_k ln[s][k] * Wq[k][t] + bq[t]
    float qa[8];
    #pragma unroll
    for (int s = 0; s < 8; s++) qa[s] = bq[t];
    for (int k = 0; k < 256; k++) {
        float wq = Wq[k * 256 + t];
        #pragma unroll
        for (int s = 0; s < 8; s++) qa[s] += s_ln[s * 256 + k] * wq;
    }
    int h = t >> 6, d = t & 63;
    for (int s = 0; s < 8; s++) q_l[(s * 4 + h) * 65 + d] = qa[s];
    __syncthreads();

    // qk: thread t -> hs = t&31, c = i*8 + (t>>5)
    int hs = t & 31, hh = hs >> 3, si = hs & 7, c0 = t >> 5;
    const float* qrow = &q_l[(si * 4 + hh) * 65];
    for (int i = 0; i < 16; i++) {
        int c = i * 8 + c0;
        const float4* wk4 = (const float4*)&Wk[c * 256 + hh * 64];
        float acc = 0.0f;
        #pragma unroll
        for (int d4 = 0; d4 < 16; d4++) {
            float4 w = wk4[d4];
            acc += w.x * qrow[d4 * 4] + w.y * qrow[d4 * 4 + 1]
                 + w.z * qrow[d4 * 4 + 2] + w.w * qrow[d4 * 4 + 3];
        }
        qk_ws[b * 4096 + c * 32 + hs] = acc;
    }
    if (t < 32) {
        int h2 = t >> 3, s2 = t & 7;
        float acc = 0.0f;
        for (int d2 = 0; d2 < 64; d2++)
            acc += bk[h2 * 64 + d2] * q_l[(s2 * 4 + h2) * 65 + d2];
        qb_ws[b * 32 + t] = acc;
    }
}

// ---------------- Kernel 2: fused v-proj + scores(via qk) + softmax + agg --
// LDS 37KB: s_u 16KB (feats f32 [c][p]) + s_qk 8KB (bf16 [c][hs]) +
// s_attn 4KB + s_agg 8KB + s_qb. No k tile, no aliasing. All LDS patterns
// are broadcast or distinct-bank (verified mod-32 arithmetic).
__global__ __launch_bounds__(256) void k_attn(
    const float* __restrict__ feat,   // (B,128,4096)
    const float* __restrict__ Wv, const float* __restrict__ bv,
    const float* __restrict__ qk_ws, const float* __restrict__ qb_ws,
    float* __restrict__ agg_ws)
{
    int t = threadIdx.x, b = blockIdx.y, n0 = blockIdx.x * 128;
    __shared__ __align__(16) float s_u[4096];   // feats [c][p=32]
    __shared__ __hip_bfloat16 s_qk[4096];       // [c][hs]
    __shared__ float s_qb[32];
    __shared__ float s_attn[1024];              // [p][hs]
    __shared__ float s_agg[2048];               // [s][d]

    for (int i = 0; i < 16; i++)
        s_qk[i * 256 + t] = __float2bfloat16(qk_ws[b * 4096 + i * 256 + t]);
    if (t < 32) s_qb[t] = qb_ws[b * 32 + t];
    for (int i = 0; i < 8; i++) s_agg[i * 256 + t] = 0.0f;
    float bvt = bv[t];
    int hs = t & 31, myq = t >> 5;

    for (int tt = 0; tt < 4; ++tt) {
        __syncthreads();             // prev-iter s_attn readers done; s_u reuse safe
        int nb = n0 + tt * 32;
        for (int i = 0; i < 16; i++) {
            int idx = i * 256 + t, c = idx >> 5, p = idx & 31;
            s_u[c * 32 + p] = feat[(size_t)b * (FDIM * NPOS) + (size_t)c * NPOS + nb + p];
        }
        __syncthreads();

        float av[32], sc[4];
        #pragma unroll
        for (int p = 0; p < 32; p++) av[p] = 0.0f;
        sc[0] = sc[1] = sc[2] = sc[3] = 0.0f;

        for (int c = 0; c < FDIM; c++) {
            float wv  = Wv[c * SDIM + t];           // coalesced, L2-hot
            float qkc = bf2f(s_qk[c * 32 + hs]);    // conflict-free (dword=hs-pair)
            const float4* f4 = (const float4*)&s_u[c * 32];  // uniform broadcast
            float4 fq = f4[myq];                    // this thread's score p-quad
            #pragma unroll
            for (int pb = 0; pb < 8; pb++) {
                float4 f = f4[pb];
                av[pb*4+0] += f.x * wv; av[pb*4+1] += f.y * wv;
                av[pb*4+2] += f.z * wv; av[pb*4+3] += f.w * wv;
            }
            sc[0] += fq.x * qkc; sc[1] += fq.y * qkc;
            sc[2] += fq.z * qkc; sc[3] += fq.w * qkc;
        }

        // scores -> s_attn: thread owns p = myq*4+j, col hs (bank=hs: free)
        #pragma unroll
        for (int j = 0; j < 4; j++)
            s_attn[(myq * 4 + j) * 32 + hs] = (sc[j] + s_qb[hs]) * 0.125f;
        __syncthreads();

        // softmax over the 8 slots, per (p, h)
        if (t < 128) {
            int p = t >> 2, h2 = t & 3;
            float* a = &s_attn[p * 32 + h2 * 8];
            float m = a[0];
            for (int s = 1; s < 8; s++) m = fmaxf(m, a[s]);
            float e[8], ssum = 0.0f;
            for (int s = 0; s < 8; s++) { e[s] = __expf(a[s] - m); ssum += e[s]; }
            float inv = 1.0f / ssum;
            for (int s = 0; s < 8; s++) a[s] = e[s] * inv;
        }
        __syncthreads();

        // agg: thread t owns dim d=t (head h=t>>6); v[p][t] = av[p]+bvt (regs)
        int h = t >> 6;
        float accs[8];
        #pragma unroll
        for (int s = 0; s < 8; s++) accs[s] = 0.0f;
        for (int p = 0; p < 32; p++) {
            float vp = av[p] + bvt;
            const float* ap = &s_attn[p * 32 + h * 8];   // all-lane broadcast
            #pragma unroll
            for (int s = 0; s < 8; s++) accs[s] += ap[s] * vp;
        }
        #pragma unroll
        for (int s = 0; s < 8; s++) s_agg[s * 256 + t] += accs[s];
    }
    __syncthreads();
    for (int i = 0; i < 8; i++)
        atomicAdd(&agg_ws[b * 2048 + i * 256 + t], s_agg[i * 256 + t]);
}

// ---------------- Kernel 3: GRU cell + post-LN + MLP + residual ------------
// agg lives in d_out; each block reads its own slice then overwrites it.
__global__ __launch_bounds__(256) void k_gru(
    const float* __restrict__ slots,
    const float* __restrict__ W_ih, const float* __restrict__ b_ih,
    const float* __restrict__ W_hh, const float* __restrict__ b_hh,
    const float* __restrict__ g_post, const float* __restrict__ b_post,
    const float* __restrict__ W1, const float* __restrict__ b1,
    const float* __restrict__ W2, const float* __restrict__ b2,
    float* __restrict__ out)   // in: agg accumulator, out: final
{
    int row = blockIdx.x, t = threadIdx.x;   // row = b*8 + s
    __shared__ float s_x[256], s_h[256], s_ln[256], s_y1[512];
    __shared__ float r1[256], r2[256];

    float xv = out[row * 256 + t];           // agg (atomics completed)
    float hv = slots[row * 256 + t];
    s_x[t] = xv; s_h[t] = hv;
    __syncthreads();

    float gi[3], gh[3];
    const float4* sx4 = (const float4*)s_x;
    const float4* sh4 = (const float4*)s_h;
    for (int g = 0; g < 3; g++) {
        int j = g * 256 + t;
        float a1 = b_ih[j], a2 = b_hh[j];
        const float4* wi4 = (const float4*)(W_ih + (size_t)j * 256);
        const float4* wh4 = (const float4*)(W_hh + (size_t)j * 256);
        for (int k = 0; k < 64; k++) {
            float4 wi = wi4[k], xb = sx4[k];
            a1 += wi.x * xb.x + wi.y * xb.y + wi.z * xb.z + wi.w * xb.w;
            float4 wh = wh4[k], hb = sh4[k];
            a2 += wh.x * hb.x + wh.y * hb.y + wh.z * hb.z + wh.w * hb.w;
        }
        gi[g] = a1; gh[g] = a2;
    }
    float r  = 1.0f / (1.0f + __expf(-(gi[0] + gh[0])));
    float z  = 1.0f / (1.0f + __expf(-(gi[1] + gh[1])));
    float nn = tanhf(gi[2] + r * gh[2]);
    float hnew = (1.0f - z) * nn + z * hv;

    r1[t] = hnew; r2[t] = hnew * hnew;
    __syncthreads();
    for (int o = 128; o > 0; o >>= 1) {
        if (t < o) { r1[t] += r1[t + o]; r2[t] += r2[t + o]; }
        __syncthreads();
    }
    float mu  = r1[0] * (1.0f / 256);
    float var = r2[0] * (1.0f / 256) - mu * mu;
    float ln = (hnew - mu) * rsqrtf(var + 1e-5f) * g_post[t] + b_post[t];
    s_ln[t] = ln;
    __syncthreads();

    for (int i = 0; i < 2; i++) {
        int j = i * 256 + t;
        float a = b1[j];
        for (int k = 0; k < 256; k++) a += s_ln[k] * W1[k * 512 + j];
        s_y1[j] = fmaxf(a, 0.0f);
    }
    __syncthreads();

    float o = hnew + b2[t];
    for (int j = 0; j < 512; j++) o += s_y1[j] * W2[j * 256 + t];
    out[row * 256 + t] = o;
}

extern "C" void kernel_launch(void* const* d_in, const int* in_sizes, int n_in,
                              void* d_out, int out_size, void* d_ws, size_t ws_size,
                              hipStream_t stream) {
    const float* features = (const float*)d_in[0];
    const float* slots    = (const float*)d_in[1];
    const float* Wq   = (const float*)d_in[2];
    const float* bq   = (const float*)d_in[3];
    const float* Wk   = (const float*)d_in[4];
    const float* bk   = (const float*)d_in[5];
    const float* Wv   = (const float*)d_in[6];
    const float* bv   = (const float*)d_in[7];
    const float* W_ih = (const float*)d_in[8];
    const float* b_ih = (const float*)d_in[9];
    const float* W_hh = (const float*)d_in[10];
    const float* b_hh = (const float*)d_in[11];
    const float* g_pre  = (const float*)d_in[12];
    const float* b_pre  = (const float*)d_in[13];
    const float* g_post = (const float*)d_in[14];
    const float* b_post = (const float*)d_in[15];
    const float* W1 = (const float*)d_in[16];
    const float* b1 = (const float*)d_in[17];
    const float* W2 = (const float*)d_in[18];
    const float* b2 = (const float*)d_in[19];
    float* out = (float*)d_out;

    // agg accumulator lives in d_out (65536 f32, zeroed by k_prep, fully
    // overwritten by k_gru). d_ws: qk (512KB) + qb (4KB).
    float* qk_ws = (float*)d_ws;               // 32*128*32 f32
    float* qb_ws = qk_ws + 32 * 4096;          // 32*32 f32
    float* agg_ws = out;

    k_prep<<<dim3(32), dim3(256), 0, stream>>>(slots, Wq, bq, g_pre, b_pre,
                                               Wk, bk, qk_ws, qb_ws, agg_ws);
    k_attn<<<dim3(32, 32), dim3(256), 0, stream>>>(features, Wv, bv, qk_ws, qb_ws, agg_ws);
    k_gru<<<dim3(256), dim3(256), 0, stream>>>(slots, W_ih, b_ih, W_hh, b_hh,
                                               g_post, b_post, W1, b1, W2, b2, out);
}

// Round 7
// 310.670 us; speedup vs baseline: 2.9442x; 1.3465x over previous
//
#include <hip/hip_runtime.h>
#include <hip/hip_bf16.h>

#define NSLOT 8
#define SDIM 256
#define FDIM 128
#define NHEAD 4
#define HDIM 64
#define NPOS 4096

// ---------------- Kernel 1 (8 blocks per batch): LN(slots), q = LN@Wq+bq,
// then each block computes 16 channels of qk[c][hs] = sum_d Wk[c][h64+d]*q[s][h64+d].
// chunk 0 also writes qb and zeroes this batch's agg slice (in d_out).
__global__ __launch_bounds__(256) void k_prep(
    const float* __restrict__ slots,
    const float* __restrict__ Wq, const float* __restrict__ bq,
    const float* __restrict__ g_pre, const float* __restrict__ b_pre,
    const float* __restrict__ Wk, const float* __restrict__ bk,
    float* __restrict__ qk_ws, float* __restrict__ qb_ws,
    float* __restrict__ agg_ws)
{
    int blk = blockIdx.x;            // 256 blocks: b = blk>>3, chunk = blk&7
    int b = blk >> 3, chunk = blk & 7;
    int t = threadIdx.x;
    __shared__ float s_ln[8 * 256];
    __shared__ float q_l[32 * 65];   // [(s*4+h)*65 + d] — stride 65: conflict-free
    __shared__ float red1[256], red2[256];

    if (chunk == 0)
        for (int i = 0; i < 8; i++) agg_ws[b * 2048 + i * 256 + t] = 0.0f;

    // LN: thread t -> row s8 = t>>5, covers 8 elements
    int s8 = t >> 5, lane = t & 31;
    float xv[8], sum = 0.0f, sq = 0.0f;
    for (int u = 0; u < 8; u++) {
        float x = slots[(b * 8 + s8) * 256 + lane * 8 + u];
        xv[u] = x; sum += x; sq += x * x;
    }
    red1[t] = sum; red2[t] = sq;
    __syncthreads();
    for (int o = 16; o > 0; o >>= 1) {
        if (lane < o) { red1[t] += red1[t + o]; red2[t] += red2[t + o]; }
        __syncthreads();
    }
    float mu  = red1[s8 * 32] * (1.0f / 256);
    float var = red2[s8 * 32] * (1.0f / 256) - mu * mu;
    float rstd = rsqrtf(var + 1e-5f);
    for (int u = 0; u < 8; u++) {
        int j = lane * 8 + u;
        s_ln[s8 * 256 + j] = (xv[u] - mu) * rstd * g_pre[j] + b_pre[j];
    }
    __syncthreads();

    // q[s][t] = sum_k ln[s][k] * Wq[k][t] + bq[t]   (duplicated across chunks; cheap)
    float qa[8];
    #pragma unroll
    for (int s = 0; s < 8; s++) qa[s] = bq[t];
    for (int k = 0; k < 256; k++) {
        float wq = Wq[k * 256 + t];
        #pragma unroll
        for (int s = 0; s < 8; s++) qa[s] += s_ln[s * 256 + k] * wq;
    }
    int h = t >> 6, d = t & 63;
    for (int s = 0; s < 8; s++) q_l[(s * 4 + h) * 65 + d] = qa[s];
    __syncthreads();

    // qk for this chunk's 16 channels: c = chunk*16 + i*8 + (t>>5), i=0..1
    int hs = t & 31, hh = hs >> 3, si = hs & 7, c0 = t >> 5;
    const float* qrow = &q_l[(si * 4 + hh) * 65];
    for (int i = 0; i < 2; i++) {
        int c = chunk * 16 + i * 8 + c0;
        const float4* wk4 = (const float4*)&Wk[c * 256 + hh * 64];
        float acc = 0.0f;
        #pragma unroll
        for (int d4 = 0; d4 < 16; d4++) {
            float4 w = wk4[d4];
            acc += w.x * qrow[d4 * 4] + w.y * qrow[d4 * 4 + 1]
                 + w.z * qrow[d4 * 4 + 2] + w.w * qrow[d4 * 4 + 3];
        }
        qk_ws[b * 4096 + c * 32 + hs] = acc;
    }
    if (chunk == 0 && t < 32) {
        int h2 = t >> 3, s2 = t & 7;
        float acc = 0.0f;
        for (int d2 = 0; d2 < 64; d2++)
            acc += bk[h2 * 64 + d2] * q_l[(s2 * 4 + h2) * 65 + d2];
        qb_ws[b * 32 + t] = acc;
    }
}

// ---------------- Kernel 2: scores(qk) + softmax + attF accumulation + one
// tiny GEMM per block:  agg[s][d] = sum_c attF[h8+s][c]*Wv[c][d] + S[h8+s]*bv[d]
// where attF[hs][c] = sum_p attn[p][hs]*feat[c][p] accumulates in REGISTERS
// across the block's 4 position-tiles (v-projection folded away entirely).
// LDS ~38KB: s_buf 18KB (feats [c][36] padded; later attF [c][32], c<=128) +
// s_qk 16KB (f32) + s_attn 4KB + s_qb. All patterns <=2-way (free) by bank math.
__global__ __launch_bounds__(256, 4) void k_attn(
    const float* __restrict__ feat,   // (B,128,4096)
    const float* __restrict__ Wv, const float* __restrict__ bv,
    const float* __restrict__ qk_ws, const float* __restrict__ qb_ws,
    float* __restrict__ agg_ws)
{
    int t = threadIdx.x, b = blockIdx.y, n0 = blockIdx.x * 128;
    __shared__ __align__(16) float s_buf[128 * 36];  // feats [c][p] stride 36; attF [c][hs] stride 32 (129 rows)
    __shared__ __align__(16) float s_qk[4096];       // [c][hs] f32
    __shared__ float s_attn[1024];                   // [p][hs]
    __shared__ float s_qb[32];

    {   // stage qk (f32, float4)
        const float4* src = (const float4*)(qk_ws + b * 4096);
        float4* dst = (float4*)s_qk;
        for (int i = 0; i < 4; i++) dst[i * 256 + t] = src[i * 256 + t];
    }
    if (t < 32) s_qb[t] = qb_ws[b * 32 + t];

    int hs = t & 31, grp = t >> 5;   // grp in 0..7: p-quad / c-offset ownership
    float attF[16];
    #pragma unroll
    for (int k = 0; k < 16; k++) attF[k] = 0.0f;
    float Ssum = 0.0f;

    for (int tt = 0; tt < 4; ++tt) {
        __syncthreads();             // prev-iter s_buf/s_attn readers done
        int nb = n0 + tt * 32;
        for (int i = 0; i < 16; i++) {
            int idx = i * 256 + t, c = idx >> 5, p = idx & 31;
            s_buf[c * 36 + p] = feat[(size_t)b * (FDIM * NPOS) + (size_t)c * NPOS + nb + p];
        }
        __syncthreads();

        // scores: thread owns positions grp*4..+3, slot-head column hs
        float sc0 = 0, sc1 = 0, sc2 = 0, sc3 = 0;
        for (int c = 0; c < 128; c++) {
            float qkc = s_qk[c * 32 + hs];                    // broadcast-pair: free
            float4 f = *(const float4*)&s_buf[c * 36 + grp * 4];  // 8 quads cover 32 banks
            sc0 += f.x * qkc; sc1 += f.y * qkc;
            sc2 += f.z * qkc; sc3 += f.w * qkc;
        }
        float qb = s_qb[hs];
        s_attn[(grp * 4 + 0) * 32 + hs] = (sc0 + qb) * 0.125f;
        s_attn[(grp * 4 + 1) * 32 + hs] = (sc1 + qb) * 0.125f;
        s_attn[(grp * 4 + 2) * 32 + hs] = (sc2 + qb) * 0.125f;
        s_attn[(grp * 4 + 3) * 32 + hs] = (sc3 + qb) * 0.125f;
        __syncthreads();

        // softmax over the 8 slots, per (p, h)  [pattern measured conflict-cheap]
        if (t < 128) {
            int p = t >> 2, h2 = t & 3;
            float* a = &s_attn[p * 32 + h2 * 8];
            float m = a[0];
            for (int s = 1; s < 8; s++) m = fmaxf(m, a[s]);
            float e[8], ssum = 0.0f;
            for (int s = 0; s < 8; s++) { e[s] = __expf(a[s] - m); ssum += e[s]; }
            float inv = 1.0f / ssum;
            for (int s = 0; s < 8; s++) a[s] = e[s] * inv;
        }
        __syncthreads();

        // attF accumulation: thread owns (hs, c = grp+8k for k=0..15)
        #pragma unroll
        for (int j = 0; j < 8; j++) {
            float a0 = s_attn[(j * 4 + 0) * 32 + hs];   // broadcast-pair: free
            float a1 = s_attn[(j * 4 + 1) * 32 + hs];
            float a2 = s_attn[(j * 4 + 2) * 32 + hs];
            float a3 = s_attn[(j * 4 + 3) * 32 + hs];
            Ssum += a0 + a1 + a2 + a3;
            #pragma unroll
            for (int k = 0; k < 16; k++) {
                float4 f = *(const float4*)&s_buf[(grp + 8 * k) * 36 + j * 4];  // 2-addr bcast
                attF[k] += a0 * f.x + a1 * f.y + a2 * f.z + a3 * f.w;
            }
        }
    }
    __syncthreads();                 // feats view of s_buf is dead
    #pragma unroll
    for (int k = 0; k < 16; k++)
        s_buf[(grp + 8 * k) * 32 + hs] = attF[k];       // bank hs, 2-way: free
    if (grp == 0) s_buf[128 * 32 + hs] = Ssum;          // rowsum channel
    __syncthreads();

    // mini-GEMM: agg[s][t] = sum_c attF[c][h*8+s]*Wv[c][t] + S[h*8+s]*bv[t]
    int h = t >> 6;
    float acc[8];
    #pragma unroll
    for (int s = 0; s < 8; s++) acc[s] = 0.0f;
    for (int c = 0; c < 128; c++) {
        float wv = Wv[c * 256 + t];                      // coalesced, L2-hot
        float4 A0 = *(const float4*)&s_buf[c * 32 + h * 8];      // uniform bcast
        float4 A1 = *(const float4*)&s_buf[c * 32 + h * 8 + 4];
        acc[0] += A0.x * wv; acc[1] += A0.y * wv; acc[2] += A0.z * wv; acc[3] += A0.w * wv;
        acc[4] += A1.x * wv; acc[5] += A1.y * wv; acc[6] += A1.z * wv; acc[7] += A1.w * wv;
    }
    float bvt = bv[t];
    float4 S0 = *(const float4*)&s_buf[128 * 32 + h * 8];
    float4 S1 = *(const float4*)&s_buf[128 * 32 + h * 8 + 4];
    acc[0] += S0.x * bvt; acc[1] += S0.y * bvt; acc[2] += S0.z * bvt; acc[3] += S0.w * bvt;
    acc[4] += S1.x * bvt; acc[5] += S1.y * bvt; acc[6] += S1.z * bvt; acc[7] += S1.w * bvt;

    #pragma unroll
    for (int s = 0; s < 8; s++)
        atomicAdd(&agg_ws[b * 2048 + s * 256 + t], acc[s]);
}

// ---------------- Kernel 3: GRU cell + post-LN + MLP + residual ------------
// agg lives in d_out; each block reads its own slice then overwrites it.
__global__ __launch_bounds__(256) void k_gru(
    const float* __restrict__ slots,
    const float* __restrict__ W_ih, const float* __restrict__ b_ih,
    const float* __restrict__ W_hh, const float* __restrict__ b_hh,
    const float* __restrict__ g_post, const float* __restrict__ b_post,
    const float* __restrict__ W1, const float* __restrict__ b1,
    const float* __restrict__ W2, const float* __restrict__ b2,
    float* __restrict__ out)   // in: agg accumulator, out: final
{
    int row = blockIdx.x, t = threadIdx.x;   // row = b*8 + s
    __shared__ float s_x[256], s_h[256], s_ln[256], s_y1[512];
    __shared__ float r1[256], r2[256];

    float xv = out[row * 256 + t];           // agg (atomics completed)
    float hv = slots[row * 256 + t];
    s_x[t] = xv; s_h[t] = hv;
    __syncthreads();

    float gi[3], gh[3];
    const float4* sx4 = (const float4*)s_x;
    const float4* sh4 = (const float4*)s_h;
    for (int g = 0; g < 3; g++) {
        int j = g * 256 + t;
        float a1 = b_ih[j], a2 = b_hh[j];
        const float4* wi4 = (const float4*)(W_ih + (size_t)j * 256);
        const float4* wh4 = (const float4*)(W_hh + (size_t)j * 256);
        for (int k = 0; k < 64; k++) {
            float4 wi = wi4[k], xb = sx4[k];
            a1 += wi.x * xb.x + wi.y * xb.y + wi.z * xb.z + wi.w * xb.w;
            float4 wh = wh4[k], hb = sh4[k];
            a2 += wh.x * hb.x + wh.y * hb.y + wh.z * hb.z + wh.w * hb.w;
        }
        gi[g] = a1; gh[g] = a2;
    }
    float r  = 1.0f / (1.0f + __expf(-(gi[0] + gh[0])));
    float z  = 1.0f / (1.0f + __expf(-(gi[1] + gh[1])));
    float nn = tanhf(gi[2] + r * gh[2]);
    float hnew = (1.0f - z) * nn + z * hv;

    r1[t] = hnew; r2[t] = hnew * hnew;
    __syncthreads();
    for (int o = 128; o > 0; o >>= 1) {
        if (t < o) { r1[t] += r1[t + o]; r2[t] += r2[t + o]; }
        __syncthreads();
    }
    float mu  = r1[0] * (1.0f / 256);
    float var = r2[0] * (1.0f / 256) - mu * mu;
    float ln = (hnew - mu) * rsqrtf(var + 1e-5f) * g_post[t] + b_post[t];
    s_ln[t] = ln;
    __syncthreads();

    for (int i = 0; i < 2; i++) {
        int j = i * 256 + t;
        float a = b1[j];
        for (int k = 0; k < 256; k++) a += s_ln[k] * W1[k * 512 + j];
        s_y1[j] = fmaxf(a, 0.0f);
    }
    __syncthreads();

    float o = hnew + b2[t];
    for (int j = 0; j < 512; j++) o += s_y1[j] * W2[j * 256 + t];
    out[row * 256 + t] = o;
}

extern "C" void kernel_launch(void* const* d_in, const int* in_sizes, int n_in,
                              void* d_out, int out_size, void* d_ws, size_t ws_size,
                              hipStream_t stream) {
    const float* features = (const float*)d_in[0];
    const float* slots    = (const float*)d_in[1];
    const float* Wq   = (const float*)d_in[2];
    const float* bq   = (const float*)d_in[3];
    const float* Wk   = (const float*)d_in[4];
    const float* bk   = (const float*)d_in[5];
    const float* Wv   = (const float*)d_in[6];
    const float* bv   = (const float*)d_in[7];
    const float* W_ih = (const float*)d_in[8];
    const float* b_ih = (const float*)d_in[9];
    const float* W_hh = (const float*)d_in[10];
    const float* b_hh = (const float*)d_in[11];
    const float* g_pre  = (const float*)d_in[12];
    const float* b_pre  = (const float*)d_in[13];
    const float* g_post = (const float*)d_in[14];
    const float* b_post = (const float*)d_in[15];
    const float* W1 = (const float*)d_in[16];
    const float* b1 = (const float*)d_in[17];
    const float* W2 = (const float*)d_in[18];
    const float* b2 = (const float*)d_in[19];
    float* out = (float*)d_out;

    // agg accumulator lives in d_out (zeroed by k_prep chunk0, overwritten by
    // k_gru). d_ws: qk f32 (512KB) + qb (4KB).
    float* qk_ws = (float*)d_ws;               // 32*4096 f32: [b][c][hs]
    float* qb_ws = qk_ws + 32 * 4096;          // 32*32 f32
    float* agg_ws = out;

    k_prep<<<dim3(256), dim3(256), 0, stream>>>(slots, Wq, bq, g_pre, b_pre,
                                                Wk, bk, qk_ws, qb_ws, agg_ws);
    k_attn<<<dim3(32, 32), dim3(256), 0, stream>>>(features, Wv, bv, qk_ws, qb_ws, agg_ws);
    k_gru<<<dim3(256), dim3(256), 0, stream>>>(slots, W_ih, b_ih, W_hh, b_hh,
                                               g_post, b_post, W1, b1, W2, b2, out);
}

// Round 8
// 256.257 us; speedup vs baseline: 3.5694x; 1.2123x over previous
//
#include <hip/hip_runtime.h>
#include <hip/hip_bf16.h>

#define NSLOT 8
#define SDIM 256
#define FDIM 128
#define NHEAD 4
#define HDIM 64
#define NPOS 4096

typedef short v8s __attribute__((ext_vector_type(8)));
typedef short v4s __attribute__((ext_vector_type(4)));
typedef float v4f __attribute__((ext_vector_type(4)));

__device__ __forceinline__ unsigned short f2bf(float x) {
    __hip_bfloat16 h = __float2bfloat16(x);
    unsigned short u; __builtin_memcpy(&u, &h, 2); return u;
}
__device__ __forceinline__ float bfr2f(unsigned short u) {
    __hip_bfloat16 h; __builtin_memcpy(&h, &u, 2); return __bfloat162float(h);
}

// ---------------- Kernel 1 (8 blocks per batch): LN(slots), q = LN@Wq+bq,
// qkT[b][hs][c] (bf16) = sum_d Wk[c][h64+d]*q[s][h64+d];  qb[b][hs] f32.
// chunk 0 also zeroes this batch's agg slice (which lives in d_out).
__global__ __launch_bounds__(256) void k_prep(
    const float* __restrict__ slots,
    const float* __restrict__ Wq, const float* __restrict__ bq,
    const float* __restrict__ g_pre, const float* __restrict__ b_pre,
    const float* __restrict__ Wk, const float* __restrict__ bk,
    unsigned short* __restrict__ qkT_ws, float* __restrict__ qb_ws,
    float* __restrict__ agg_ws)
{
    int blk = blockIdx.x;            // b = blk>>3, chunk = blk&7
    int b = blk >> 3, chunk = blk & 7;
    int t = threadIdx.x;
    __shared__ float s_ln[8 * 256];
    __shared__ float q_l[32 * 65];   // [(s*4+h)*65 + d] stride 65: conflict-free
    __shared__ float red1[256], red2[256];

    if (chunk == 0)
        for (int i = 0; i < 8; i++) agg_ws[b * 2048 + i * 256 + t] = 0.0f;

    int s8 = t >> 5, lane = t & 31;
    float xv[8], sum = 0.0f, sq = 0.0f;
    for (int u = 0; u < 8; u++) {
        float x = slots[(b * 8 + s8) * 256 + lane * 8 + u];
        xv[u] = x; sum += x; sq += x * x;
    }
    red1[t] = sum; red2[t] = sq;
    __syncthreads();
    for (int o = 16; o > 0; o >>= 1) {
        if (lane < o) { red1[t] += red1[t + o]; red2[t] += red2[t + o]; }
        __syncthreads();
    }
    float mu  = red1[s8 * 32] * (1.0f / 256);
    float var = red2[s8 * 32] * (1.0f / 256) - mu * mu;
    float rstd = rsqrtf(var + 1e-5f);
    for (int u = 0; u < 8; u++) {
        int j = lane * 8 + u;
        s_ln[s8 * 256 + j] = (xv[u] - mu) * rstd * g_pre[j] + b_pre[j];
    }
    __syncthreads();

    float qa[8];
    #pragma unroll
    for (int s = 0; s < 8; s++) qa[s] = bq[t];
    for (int k = 0; k < 256; k++) {
        float wq = Wq[k * 256 + t];
        #pragma unroll
        for (int s = 0; s < 8; s++) qa[s] += s_ln[s * 256 + k] * wq;
    }
    int h = t >> 6, d = t & 63;
    for (int s = 0; s < 8; s++) q_l[(s * 4 + h) * 65 + d] = qa[s];
    __syncthreads();

    // qkT bf16 for this chunk's 16 channels
    int hs = t & 31, hh = hs >> 3, si = hs & 7, c0 = t >> 5;
    const float* qrow = &q_l[(si * 4 + hh) * 65];
    for (int i = 0; i < 2; i++) {
        int c = chunk * 16 + i * 8 + c0;
        const float4* wk4 = (const float4*)&Wk[c * 256 + hh * 64];
        float acc = 0.0f;
        #pragma unroll
        for (int d4 = 0; d4 < 16; d4++) {
            float4 w = wk4[d4];
            acc += w.x * qrow[d4 * 4] + w.y * qrow[d4 * 4 + 1]
                 + w.z * qrow[d4 * 4 + 2] + w.w * qrow[d4 * 4 + 3];
        }
        qkT_ws[(b * 32 + hs) * 128 + c] = f2bf(acc);
    }
    if (chunk == 0 && t < 32) {
        int h2 = t >> 3, s2 = t & 7;
        float acc = 0.0f;
        for (int d2 = 0; d2 < 64; d2++)
            acc += bk[h2 * 64 + d2] * q_l[(s2 * 4 + h2) * 65 + d2];
        qb_ws[b * 32 + t] = acc;
    }
}

// ---------------- Kernel 2: MFMA scores + softmax + MFMA attF^T + mini-GEMM
// LDS layout (bytes):
//   [0,8704)      featPC: bf16 [p=32][c, stride 136]   (A of scores)
//   [8704,23040)  featCP: bf16 [c=128][p, stride 56]   (B of attF)
//   [0,16896)     attFT : f32  [hs=32][c, stride 132]  (ALIAS, used after loop)
//   [23040,27648) s_attn: f32  [p=32][hs, stride 36]
//   [27648,31232) s_aT  : bf16 [hs=32][p, stride 56]   (A of attF)
//   [31232,31360) s_S   : f32  [32]
__global__ __launch_bounds__(256, 4) void k_attn(
    const float* __restrict__ feat,   // (B,128,4096)
    const float* __restrict__ Wv, const float* __restrict__ bv,
    const unsigned short* __restrict__ qkT, const float* __restrict__ qb_ws,
    float* __restrict__ agg_ws)
{
    __shared__ __align__(16) char smem[31360];
    unsigned short* featPC = (unsigned short*)smem;              // stride 136
    unsigned short* featCP = (unsigned short*)(smem + 8704);     // stride 56
    float*          attFT  = (float*)smem;                       // stride 132 (alias)
    float*          s_attn = (float*)(smem + 23040);             // stride 36
    unsigned short* s_aT   = (unsigned short*)(smem + 27648);    // stride 56
    float*          s_S    = (float*)(smem + 31232);

    int t = threadIdx.x, b = blockIdx.y, n0 = blockIdx.x * 128;
    int wv_ = t >> 6, lane = t & 63, quad = lane >> 4, l16 = lane & 15;
    int mt = wv_ >> 1, nt = wv_ & 1;
    int sp  = l16 + mt * 16;         // scores A row (p)
    int shs = l16 + nt * 16;         // scores D col (hs)

    // preload B-frags (qkT) from global, and qb for this lane's hs column
    v8s bq_[4];
    #pragma unroll
    for (int ch = 0; ch < 4; ch++)
        bq_[ch] = *(const v8s*)&qkT[(b * 32 + shs) * 128 + ch * 32 + quad * 8];
    float qbv = qb_ws[b * 32 + shs];
    if (t < 32) s_S[t] = 0.0f;

    v4f accF[4];
    #pragma unroll
    for (int i = 0; i < 4; i++) accF[i] = (v4f){0.f, 0.f, 0.f, 0.f};

    int c0 = (t >> 3) * 4, p0 = (t & 7) * 4;   // staging sub-tile

    for (int tt = 0; tt < 4; ++tt) {
        __syncthreads();             // prev-iter featPC/CP & s_aT readers done
        int nb = n0 + tt * 32;
        // stage feats 4c x 4p per thread -> both bf16 layouts (b64 writes)
        float fv[4][4];
        #pragma unroll
        for (int r = 0; r < 4; r++) {
            float4 f = *(const float4*)&feat[(size_t)b * (FDIM * NPOS)
                                             + (size_t)(c0 + r) * NPOS + nb + p0];
            fv[r][0] = f.x; fv[r][1] = f.y; fv[r][2] = f.z; fv[r][3] = f.w;
        }
        #pragma unroll
        for (int r = 0; r < 4; r++)
            *(v4s*)&featCP[(c0 + r) * 56 + p0] =
                (v4s){(short)f2bf(fv[r][0]), (short)f2bf(fv[r][1]),
                      (short)f2bf(fv[r][2]), (short)f2bf(fv[r][3])};
        #pragma unroll
        for (int j = 0; j < 4; j++)
            *(v4s*)&featPC[(p0 + j) * 136 + c0] =
                (v4s){(short)f2bf(fv[0][j]), (short)f2bf(fv[1][j]),
                      (short)f2bf(fv[2][j]), (short)f2bf(fv[3][j])};
        __syncthreads();

        // scores[p][hs] = featPC @ qkT : wave computes its 16x16 (mt,nt) tile
        v4f acc = (v4f){0.f, 0.f, 0.f, 0.f};
        #pragma unroll
        for (int ch = 0; ch < 4; ch++) {
            v8s a = *(const v8s*)&featPC[sp * 136 + ch * 32 + quad * 8];
            acc = __builtin_amdgcn_mfma_f32_16x16x32_bf16(a, bq_[ch], acc, 0, 0, 0);
        }
        int pb = mt * 16 + quad * 4;
        #pragma unroll
        for (int r = 0; r < 4; r++)
            s_attn[(pb + r) * 36 + shs] = (acc[r] + qbv) * 0.125f;
        __syncthreads();

        // softmax over 8 slots per (p,h); emit bf16 attn^T [hs][p]
        if (t < 128) {
            int p = t >> 2, h2 = t & 3;
            float* a = &s_attn[p * 36 + h2 * 8];
            float m = a[0];
            for (int s = 1; s < 8; s++) m = fmaxf(m, a[s]);
            float e[8], ssum = 0.0f;
            for (int s = 0; s < 8; s++) { e[s] = __expf(a[s] - m); ssum += e[s]; }
            float inv = 1.0f / ssum;
            for (int s = 0; s < 8; s++)
                s_aT[(h2 * 8 + s) * 56 + p] = f2bf(e[s] * inv);
        }
        __syncthreads();

        // attF^T[hs][c] += attn^T @ featCP : wave owns c range wv_*32..+31
        v8s aA0 = *(const v8s*)&s_aT[l16 * 56 + quad * 8];
        v8s aA1 = *(const v8s*)&s_aT[(l16 + 16) * 56 + quad * 8];
        v8s bF0 = *(const v8s*)&featCP[(l16 + wv_ * 32) * 56 + quad * 8];
        v8s bF1 = *(const v8s*)&featCP[(l16 + wv_ * 32 + 16) * 56 + quad * 8];
        accF[0] = __builtin_amdgcn_mfma_f32_16x16x32_bf16(aA0, bF0, accF[0], 0, 0, 0);
        accF[1] = __builtin_amdgcn_mfma_f32_16x16x32_bf16(aA0, bF1, accF[1], 0, 0, 0);
        accF[2] = __builtin_amdgcn_mfma_f32_16x16x32_bf16(aA1, bF0, accF[2], 0, 0, 0);
        accF[3] = __builtin_amdgcn_mfma_f32_16x16x32_bf16(aA1, bF1, accF[3], 0, 0, 0);
        // rowsum S[hs] accumulation (post-softmax attn of this tile)
        if (t < 32) {
            float ss = 0.0f;
            for (int p = 0; p < 32; p++) ss += bfr2f(s_aT[t * 56 + p]);
            s_S[t] += ss;
        }
    }
    __syncthreads();                 // featPC/CP dead; safe to alias as attFT
    #pragma unroll
    for (int mt2 = 0; mt2 < 2; mt2++)
        #pragma unroll
        for (int ntl = 0; ntl < 2; ntl++) {
            v4f f = accF[mt2 * 2 + ntl];
            int cc = l16 + wv_ * 32 + ntl * 16;
            #pragma unroll
            for (int r = 0; r < 4; r++)
                attFT[(mt2 * 16 + quad * 4 + r) * 132 + cc] = f[r];
        }
    __syncthreads();

    // mini-GEMM: agg[s][d=t] = sum_c attFT[h*8+s][c]*Wv[c][d] + S[h*8+s]*bv[d]
    int h = t >> 6;
    float acc8[8];
    #pragma unroll
    for (int s = 0; s < 8; s++) acc8[s] = 0.0f;
    for (int chunk = 0; chunk < 32; chunk++) {
        int c4 = chunk * 4;
        float w0 = Wv[(c4 + 0) * 256 + t];
        float w1 = Wv[(c4 + 1) * 256 + t];
        float w2 = Wv[(c4 + 2) * 256 + t];
        float w3 = Wv[(c4 + 3) * 256 + t];
        #pragma unroll
        for (int s = 0; s < 8; s++) {
            v4f A = *(const v4f*)&attFT[(h * 8 + s) * 132 + c4];  // uniform bcast
            acc8[s] += A.x * w0 + A.y * w1 + A.z * w2 + A.w * w3;
        }
    }
    float bvt = bv[t];
    #pragma unroll
    for (int s = 0; s < 8; s++) acc8[s] += s_S[h * 8 + s] * bvt;
    #pragma unroll
    for (int s = 0; s < 8; s++)
        atomicAdd(&agg_ws[b * 2048 + s * 256 + t], acc8[s]);
}

// ---------------- Kernel 3: GRU + post-LN + MLP + residual, 2 rows/block ---
__global__ __launch_bounds__(256) void k_gru(
    const float* __restrict__ slots,
    const float* __restrict__ W_ih, const float* __restrict__ b_ih,
    const float* __restrict__ W_hh, const float* __restrict__ b_hh,
    const float* __restrict__ g_post, const float* __restrict__ b_post,
    const float* __restrict__ W1, const float* __restrict__ b1,
    const float* __restrict__ W2, const float* __restrict__ b2,
    float* __restrict__ out)   // in: agg accumulator, out: final
{
    int r2 = blockIdx.x, t = threadIdx.x;
    int row0 = r2 * 2, row1 = row0 + 1;
    __shared__ float s_x[2][256], s_h[2][256], s_ln[2][256], s_y1[2][512];
    __shared__ float red[4][256];

    s_x[0][t] = out[row0 * 256 + t];  s_x[1][t] = out[row1 * 256 + t];
    float hv0 = slots[row0 * 256 + t], hv1 = slots[row1 * 256 + t];
    s_h[0][t] = hv0; s_h[1][t] = hv1;
    __syncthreads();

    float gi0[3], gi1[3], gh0[3], gh1[3];
    const float4* x40 = (const float4*)s_x[0];
    const float4* x41 = (const float4*)s_x[1];
    const float4* h40 = (const float4*)s_h[0];
    const float4* h41 = (const float4*)s_h[1];
    for (int g = 0; g < 3; g++) {
        int j = g * 256 + t;
        float a10 = 0, a11 = 0, a20 = 0, a21 = 0;
        const float4* wi4 = (const float4*)(W_ih + (size_t)j * 256);
        const float4* wh4 = (const float4*)(W_hh + (size_t)j * 256);
        for (int k = 0; k < 64; k++) {
            float4 wi = wi4[k], wh = wh4[k];
            float4 xa = x40[k], xb = x41[k], ha = h40[k], hb = h41[k];
            a10 += wi.x * xa.x + wi.y * xa.y + wi.z * xa.z + wi.w * xa.w;
            a11 += wi.x * xb.x + wi.y * xb.y + wi.z * xb.z + wi.w * xb.w;
            a20 += wh.x * ha.x + wh.y * ha.y + wh.z * ha.z + wh.w * ha.w;
            a21 += wh.x * hb.x + wh.y * hb.y + wh.z * hb.z + wh.w * hb.w;
        }
        float bi = b_ih[j], bh = b_hh[j];
        gi0[g] = a10 + bi; gi1[g] = a11 + bi;
        gh0[g] = a20 + bh; gh1[g] = a21 + bh;
    }
    float r0 = 1.0f / (1.0f + __expf(-(gi0[0] + gh0[0])));
    float z0 = 1.0f / (1.0f + __expf(-(gi0[1] + gh0[1])));
    float n0 = tanhf(gi0[2] + r0 * gh0[2]);
    float hnew0 = (1.0f - z0) * n0 + z0 * hv0;
    float r1 = 1.0f / (1.0f + __expf(-(gi1[0] + gh1[0])));
    float z1 = 1.0f / (1.0f + __expf(-(gi1[1] + gh1[1])));
    float n1 = tanhf(gi1[2] + r1 * gh1[2]);
    float hnew1 = (1.0f - z1) * n1 + z1 * hv1;

    red[0][t] = hnew0; red[1][t] = hnew0 * hnew0;
    red[2][t] = hnew1; red[3][t] = hnew1 * hnew1;
    __syncthreads();
    for (int o = 128; o > 0; o >>= 1) {
        if (t < o)
            for (int q = 0; q < 4; q++) red[q][t] += red[q][t + o];
        __syncthreads();
    }
    float mu0 = red[0][0] * (1.0f / 256), var0 = red[1][0] * (1.0f / 256) - mu0 * mu0;
    float mu1 = red[2][0] * (1.0f / 256), var1 = red[3][0] * (1.0f / 256) - mu1 * mu1;
    float gp = g_post[t], bp = b_post[t];
    s_ln[0][t] = (hnew0 - mu0) * rsqrtf(var0 + 1e-5f) * gp + bp;
    s_ln[1][t] = (hnew1 - mu1) * rsqrtf(var1 + 1e-5f) * gp + bp;
    __syncthreads();

    for (int i = 0; i < 2; i++) {
        int j = i * 256 + t;
        float bb = b1[j], a0 = bb, a1 = bb;
        for (int k = 0; k < 256; k++) {
            float w = W1[k * 512 + j];
            a0 += s_ln[0][k] * w; a1 += s_ln[1][k] * w;
        }
        s_y1[0][j] = fmaxf(a0, 0.0f); s_y1[1][j] = fmaxf(a1, 0.0f);
    }
    __syncthreads();

    float bb2 = b2[t];
    float o0 = hnew0 + bb2, o1 = hnew1 + bb2;
    for (int j = 0; j < 512; j++) {
        float w = W2[j * 256 + t];
        o0 += s_y1[0][j] * w; o1 += s_y1[1][j] * w;
    }
    out[row0 * 256 + t] = o0;
    out[row1 * 256 + t] = o1;
}

extern "C" void kernel_launch(void* const* d_in, const int* in_sizes, int n_in,
                              void* d_out, int out_size, void* d_ws, size_t ws_size,
                              hipStream_t stream) {
    const float* features = (const float*)d_in[0];
    const float* slots    = (const float*)d_in[1];
    const float* Wq   = (const float*)d_in[2];
    const float* bq   = (const float*)d_in[3];
    const float* Wk   = (const float*)d_in[4];
    const float* bk   = (const float*)d_in[5];
    const float* Wv   = (const float*)d_in[6];
    const float* bv   = (const float*)d_in[7];
    const float* W_ih = (const float*)d_in[8];
    const float* b_ih = (const float*)d_in[9];
    const float* W_hh = (const float*)d_in[10];
    const float* b_hh = (const float*)d_in[11];
    const float* g_pre  = (const float*)d_in[12];
    const float* b_pre  = (const float*)d_in[13];
    const float* g_post = (const float*)d_in[14];
    const float* b_post = (const float*)d_in[15];
    const float* W1 = (const float*)d_in[16];
    const float* b1 = (const float*)d_in[17];
    const float* W2 = (const float*)d_in[18];
    const float* b2 = (const float*)d_in[19];
    float* out = (float*)d_out;

    // ws: qkT bf16 [b][hs][c] 256KB; qb f32 4KB. agg accumulator lives in
    // d_out (zeroed by k_prep chunk0, consumed+overwritten by k_gru).
    unsigned short* qkT_ws = (unsigned short*)d_ws;
    float* qb_ws = (float*)((char*)d_ws + 32 * 32 * 128 * 2);
    float* agg_ws = out;

    k_prep<<<dim3(256), dim3(256), 0, stream>>>(slots, Wq, bq, g_pre, b_pre,
                                                Wk, bk, qkT_ws, qb_ws, agg_ws);
    k_attn<<<dim3(32, 32), dim3(256), 0, stream>>>(features, Wv, bv, qkT_ws, qb_ws, agg_ws);
    k_gru<<<dim3(128), dim3(256), 0, stream>>>(slots, W_ih, b_ih, W_hh, b_hh,
                                               g_post, b_post, W1, b1, W2, b2, out);
}

// Round 10
// 212.351 us; speedup vs baseline: 4.3074x; 1.2068x over previous
//
#include <hip/hip_runtime.h>
#include <hip/hip_bf16.h>

#define NSLOT 8
#define SDIM 256
#define FDIM 128
#define NHEAD 4
#define HDIM 64
#define NPOS 4096

typedef short v8s __attribute__((ext_vector_type(8)));
typedef short v4s __attribute__((ext_vector_type(4)));
typedef float v4f __attribute__((ext_vector_type(4)));

__device__ __forceinline__ unsigned short f2bf(float x) {
    __hip_bfloat16 h = __float2bfloat16(x);
    unsigned short u; __builtin_memcpy(&u, &h, 2); return u;
}
__device__ __forceinline__ float bfr2f(unsigned short u) {
    __hip_bfloat16 h; __builtin_memcpy(&h, &u, 2); return __bfloat162float(h);
}
__device__ __forceinline__ void split2(float x, unsigned short& hi, unsigned short& lo) {
    hi = f2bf(x);
    lo = f2bf(x - bfr2f(hi));
}

// ---------------- Kernel 1 (8 blocks per batch): LN(slots), q = LN@Wq+bq,
// qkT[b][hs][c] (bf16) = sum_d Wk[c][h64+d]*q[s][h64+d];  qb[b][hs] f32.
// chunk 0 also zeroes this batch's agg slice (which lives in d_out).
__global__ __launch_bounds__(256) void k_prep(
    const float* __restrict__ slots,
    const float* __restrict__ Wq, const float* __restrict__ bq,
    const float* __restrict__ g_pre, const float* __restrict__ b_pre,
    const float* __restrict__ Wk, const float* __restrict__ bk,
    unsigned short* __restrict__ qkT_ws, float* __restrict__ qb_ws,
    float* __restrict__ agg_ws)
{
    int blk = blockIdx.x;            // b = blk>>3, chunk = blk&7
    int b = blk >> 3, chunk = blk & 7;
    int t = threadIdx.x;
    __shared__ float s_ln[8 * 256];
    __shared__ float q_l[32 * 65];   // [(s*4+h)*65 + d] stride 65: conflict-free
    __shared__ float red1[256], red2[256];

    if (chunk == 0)
        for (int i = 0; i < 8; i++) agg_ws[b * 2048 + i * 256 + t] = 0.0f;

    int s8 = t >> 5, lane = t & 31;
    float xv[8], sum = 0.0f, sq = 0.0f;
    for (int u = 0; u < 8; u++) {
        float x = slots[(b * 8 + s8) * 256 + lane * 8 + u];
        xv[u] = x; sum += x; sq += x * x;
    }
    red1[t] = sum; red2[t] = sq;
    __syncthreads();
    for (int o = 16; o > 0; o >>= 1) {
        if (lane < o) { red1[t] += red1[t + o]; red2[t] += red2[t + o]; }
        __syncthreads();
    }
    float mu  = red1[s8 * 32] * (1.0f / 256);
    float var = red2[s8 * 32] * (1.0f / 256) - mu * mu;
    float rstd = rsqrtf(var + 1e-5f);
    for (int u = 0; u < 8; u++) {
        int j = lane * 8 + u;
        s_ln[s8 * 256 + j] = (xv[u] - mu) * rstd * g_pre[j] + b_pre[j];
    }
    __syncthreads();

    float qa[8];
    #pragma unroll
    for (int s = 0; s < 8; s++) qa[s] = bq[t];
    for (int k = 0; k < 256; k++) {
        float wq = Wq[k * 256 + t];
        #pragma unroll
        for (int s = 0; s < 8; s++) qa[s] += s_ln[s * 256 + k] * wq;
    }
    int h = t >> 6, d = t & 63;
    for (int s = 0; s < 8; s++) q_l[(s * 4 + h) * 65 + d] = qa[s];
    __syncthreads();

    // qkT bf16 for this chunk's 16 channels
    int hs = t & 31, hh = hs >> 3, si = hs & 7, c0 = t >> 5;
    const float* qrow = &q_l[(si * 4 + hh) * 65];
    for (int i = 0; i < 2; i++) {
        int c = chunk * 16 + i * 8 + c0;
        const float4* wk4 = (const float4*)&Wk[c * 256 + hh * 64];
        float acc = 0.0f;
        #pragma unroll
        for (int d4 = 0; d4 < 16; d4++) {
            float4 w = wk4[d4];
            acc += w.x * qrow[d4 * 4] + w.y * qrow[d4 * 4 + 1]
                 + w.z * qrow[d4 * 4 + 2] + w.w * qrow[d4 * 4 + 3];
        }
        qkT_ws[(b * 32 + hs) * 128 + c] = f2bf(acc);
    }
    if (chunk == 0 && t < 32) {
        int h2 = t >> 3, s2 = t & 7;
        float acc = 0.0f;
        for (int d2 = 0; d2 < 64; d2++)
            acc += bk[h2 * 64 + d2] * q_l[(s2 * 4 + h2) * 65 + d2];
        qb_ws[b * 32 + t] = acc;
    }
}

// ---------------- k_wconv: transpose W1 (256x512) -> W1T hi/lo bf16 [512][256],
// W2 (512x256) -> W2T hi/lo bf16 [256][512]. 256 blocks of 32x32 tiles.
__global__ __launch_bounds__(256) void k_wconv(
    const float* __restrict__ W1, const float* __restrict__ W2,
    unsigned short* __restrict__ W1Th, unsigned short* __restrict__ W1Tl,
    unsigned short* __restrict__ W2Th, unsigned short* __restrict__ W2Tl)
{
    int id = blockIdx.x, t = threadIdx.x;
    __shared__ float tl[32][33];
    const float* src; unsigned short *dh, *dl; int N, K, k0, n0;
    if (id < 128) { src = W1; dh = W1Th; dl = W1Tl; N = 512; K = 256;
                    k0 = (id >> 4) * 32; n0 = (id & 15) * 32; }
    else          { int i2 = id - 128; src = W2; dh = W2Th; dl = W2Tl; N = 256; K = 512;
                    k0 = (i2 >> 3) * 32; n0 = (i2 & 7) * 32; }
    for (int i = 0; i < 4; i++) {
        int idx = i * 256 + t, r = idx >> 5, c = idx & 31;
        tl[r][c] = src[(size_t)(k0 + r) * N + n0 + c];
    }
    __syncthreads();
    for (int i = 0; i < 4; i++) {
        int idx = i * 256 + t, r = idx >> 5, c = idx & 31;
        unsigned short hi, lo; split2(tl[c][r], hi, lo);
        dh[(size_t)(n0 + r) * K + k0 + c] = hi;
        dl[(size_t)(n0 + r) * K + k0 + c] = lo;
    }
}

// ---------------- Kernel 2: MFMA scores + softmax + MFMA attF^T + mini-GEMM
__global__ __launch_bounds__(256, 4) void k_attn(
    const float* __restrict__ feat,   // (B,128,4096)
    const float* __restrict__ Wv, const float* __restrict__ bv,
    const unsigned short* __restrict__ qkT, const float* __restrict__ qb_ws,
    float* __restrict__ agg_ws)
{
    __shared__ __align__(16) char smem[31360];
    unsigned short* featPC = (unsigned short*)smem;              // stride 136
    unsigned short* featCP = (unsigned short*)(smem + 8704);     // stride 56
    float*          attFT  = (float*)smem;                       // stride 132 (alias)
    float*          s_attn = (float*)(smem + 23040);             // stride 36
    unsigned short* s_aT   = (unsigned short*)(smem + 27648);    // stride 56
    float*          s_S    = (float*)(smem + 31232);

    int t = threadIdx.x, b = blockIdx.y, n0 = blockIdx.x * 128;
    int wv_ = t >> 6, lane = t & 63, quad = lane >> 4, l16 = lane & 15;
    int mt = wv_ >> 1, nt = wv_ & 1;
    int sp  = l16 + mt * 16;
    int shs = l16 + nt * 16;

    v8s bq_[4];
    #pragma unroll
    for (int ch = 0; ch < 4; ch++)
        bq_[ch] = *(const v8s*)&qkT[(b * 32 + shs) * 128 + ch * 32 + quad * 8];
    float qbv = qb_ws[b * 32 + shs];
    if (t < 32) s_S[t] = 0.0f;

    v4f accF[4];
    #pragma unroll
    for (int i = 0; i < 4; i++) accF[i] = (v4f){0.f, 0.f, 0.f, 0.f};

    int c0 = (t >> 3) * 4, p0 = (t & 7) * 4;

    for (int tt = 0; tt < 4; ++tt) {
        __syncthreads();
        int nb = n0 + tt * 32;
        float fv[4][4];
        #pragma unroll
        for (int r = 0; r < 4; r++) {
            float4 f = *(const float4*)&feat[(size_t)b * (FDIM * NPOS)
                                             + (size_t)(c0 + r) * NPOS + nb + p0];
            fv[r][0] = f.x; fv[r][1] = f.y; fv[r][2] = f.z; fv[r][3] = f.w;
        }
        #pragma unroll
        for (int r = 0; r < 4; r++)
            *(v4s*)&featCP[(c0 + r) * 56 + p0] =
                (v4s){(short)f2bf(fv[r][0]), (short)f2bf(fv[r][1]),
                      (short)f2bf(fv[r][2]), (short)f2bf(fv[r][3])};
        #pragma unroll
        for (int j = 0; j < 4; j++)
            *(v4s*)&featPC[(p0 + j) * 136 + c0] =
                (v4s){(short)f2bf(fv[0][j]), (short)f2bf(fv[1][j]),
                      (short)f2bf(fv[2][j]), (short)f2bf(fv[3][j])};
        __syncthreads();

        v4f acc = (v4f){0.f, 0.f, 0.f, 0.f};
        #pragma unroll
        for (int ch = 0; ch < 4; ch++) {
            v8s a = *(const v8s*)&featPC[sp * 136 + ch * 32 + quad * 8];
            acc = __builtin_amdgcn_mfma_f32_16x16x32_bf16(a, bq_[ch], acc, 0, 0, 0);
        }
        int pb = mt * 16 + quad * 4;
        #pragma unroll
        for (int r = 0; r < 4; r++)
            s_attn[(pb + r) * 36 + shs] = (acc[r] + qbv) * 0.125f;
        __syncthreads();

        if (t < 128) {
            int p = t >> 2, h2 = t & 3;
            float* a = &s_attn[p * 36 + h2 * 8];
            float m = a[0];
            for (int s = 1; s < 8; s++) m = fmaxf(m, a[s]);
            float e[8], ssum = 0.0f;
            for (int s = 0; s < 8; s++) { e[s] = __expf(a[s] - m); ssum += e[s]; }
            float inv = 1.0f / ssum;
            for (int s = 0; s < 8; s++)
                s_aT[(h2 * 8 + s) * 56 + p] = f2bf(e[s] * inv);
        }
        __syncthreads();

        v8s aA0 = *(const v8s*)&s_aT[l16 * 56 + quad * 8];
        v8s aA1 = *(const v8s*)&s_aT[(l16 + 16) * 56 + quad * 8];
        v8s bF0 = *(const v8s*)&featCP[(l16 + wv_ * 32) * 56 + quad * 8];
        v8s bF1 = *(const v8s*)&featCP[(l16 + wv_ * 32 + 16) * 56 + quad * 8];
        accF[0] = __builtin_amdgcn_mfma_f32_16x16x32_bf16(aA0, bF0, accF[0], 0, 0, 0);
        accF[1] = __builtin_amdgcn_mfma_f32_16x16x32_bf16(aA0, bF1, accF[1], 0, 0, 0);
        accF[2] = __builtin_amdgcn_mfma_f32_16x16x32_bf16(aA1, bF0, accF[2], 0, 0, 0);
        accF[3] = __builtin_amdgcn_mfma_f32_16x16x32_bf16(aA1, bF1, accF[3], 0, 0, 0);
        if (t < 32) {
            float ss = 0.0f;
            for (int p = 0; p < 32; p++) ss += bfr2f(s_aT[t * 56 + p]);
            s_S[t] += ss;
        }
    }
    __syncthreads();
    #pragma unroll
    for (int mt2 = 0; mt2 < 2; mt2++)
        #pragma unroll
        for (int ntl = 0; ntl < 2; ntl++) {
            v4f f = accF[mt2 * 2 + ntl];
            int cc = l16 + wv_ * 32 + ntl * 16;
            #pragma unroll
            for (int r = 0; r < 4; r++)
                attFT[(mt2 * 16 + quad * 4 + r) * 132 + cc] = f[r];
        }
    __syncthreads();

    int h = t >> 6;
    float acc8[8];
    #pragma unroll
    for (int s = 0; s < 8; s++) acc8[s] = 0.0f;
    for (int chunk = 0; chunk < 32; chunk++) {
        int c4 = chunk * 4;
        float w0 = Wv[(c4 + 0) * 256 + t];
        float w1 = Wv[(c4 + 1) * 256 + t];
        float w2 = Wv[(c4 + 2) * 256 + t];
        float w3 = Wv[(c4 + 3) * 256 + t];
        #pragma unroll
        for (int s = 0; s < 8; s++) {
            v4f A = *(const v4f*)&attFT[(h * 8 + s) * 132 + c4];
            acc8[s] += A.x * w0 + A.y * w1 + A.z * w2 + A.w * w3;
        }
    }
    float bvt = bv[t];
    #pragma unroll
    for (int s = 0; s < 8; s++) acc8[s] += s_S[h * 8 + s] * bvt;
    #pragma unroll
    for (int s = 0; s < 8; s++)
        atomicAdd(&agg_ws[b * 2048 + s * 256 + t], acc8[s]);
}

// ---------------- k_gate: G[256][1536] = [x@W_ih^T + b_ih | h@W_hh^T + b_hh]
// Split-bf16 MFMA (3 per tile-K): effectively f32 precision. A staged hi/lo
// in LDS; B split in-flight from f32 global (L2-hot).
__global__ __launch_bounds__(256) void k_gate(
    const float* __restrict__ agg, const float* __restrict__ slots,
    const float* __restrict__ W_ih, const float* __restrict__ b_ih,
    const float* __restrict__ W_hh, const float* __restrict__ b_hh,
    float* __restrict__ G)
{
    int ntile = blockIdx.x, mtile = blockIdx.y, t = threadIdx.x;
    bool hhalf = ntile >= 12;
    int jbase = (hhalf ? ntile - 12 : ntile) * 64;
    const float* X    = hhalf ? slots : agg;
    const float* W    = hhalf ? W_hh : W_ih;
    const float* bias = hhalf ? b_hh : b_ih;
    int gofs = hhalf ? 768 : 0;
    int m0 = mtile * 64;

    __shared__ __align__(16) unsigned short aH[64][264];
    __shared__ __align__(16) unsigned short aL[64][264];
    for (int i = 0; i < 16; i++) {
        int idx = i * 256 + t;
        int r = idx >> 6, q = idx & 63;
        float4 f = *(const float4*)&X[(size_t)(m0 + r) * 256 + q * 4];
        unsigned short h0,l0,h1,l1,h2,l2,h3,l3;
        split2(f.x, h0, l0); split2(f.y, h1, l1);
        split2(f.z, h2, l2); split2(f.w, h3, l3);
        *(v4s*)&aH[r][q * 4] = (v4s){(short)h0,(short)h1,(short)h2,(short)h3};
        *(v4s*)&aL[r][q * 4] = (v4s){(short)l0,(short)l1,(short)l2,(short)l3};
    }
    __syncthreads();

    int w = t >> 6, lane = t & 63, quad = lane >> 4, l16 = lane & 15;
    int am = w * 16 + l16;
    for (int s = 0; s < 4; s++) {
        int jrow = jbase + s * 16 + l16;
        v4f acc = (v4f){0.f, 0.f, 0.f, 0.f};
        #pragma unroll
        for (int kk = 0; kk < 8; kk++) {
            v8s ah = *(const v8s*)&aH[am][kk * 32 + quad * 8];
            v8s al = *(const v8s*)&aL[am][kk * 32 + quad * 8];
            const float* wp = &W[(size_t)jrow * 256 + kk * 32 + quad * 8];
            float4 w0 = *(const float4*)wp;
            float4 w1 = *(const float4*)(wp + 4);
            unsigned short bh[8], bl[8];
            split2(w0.x, bh[0], bl[0]); split2(w0.y, bh[1], bl[1]);
            split2(w0.z, bh[2], bl[2]); split2(w0.w, bh[3], bl[3]);
            split2(w1.x, bh[4], bl[4]); split2(w1.y, bh[5], bl[5]);
            split2(w1.z, bh[6], bl[6]); split2(w1.w, bh[7], bl[7]);
            v8s bhi = (v8s){(short)bh[0],(short)bh[1],(short)bh[2],(short)bh[3],
                            (short)bh[4],(short)bh[5],(short)bh[6],(short)bh[7]};
            v8s blo = (v8s){(short)bl[0],(short)bl[1],(short)bl[2],(short)bl[3],
                            (short)bl[4],(short)bl[5],(short)bl[6],(short)bl[7]};
            acc = __builtin_amdgcn_mfma_f32_16x16x32_bf16(al, bhi, acc, 0, 0, 0);
            acc = __builtin_amdgcn_mfma_f32_16x16x32_bf16(ah, blo, acc, 0, 0, 0);
            acc = __builtin_amdgcn_mfma_f32_16x16x32_bf16(ah, bhi, acc, 0, 0, 0);
        }
        float bv_ = bias[jrow];
        int gj = gofs + jbase + s * 16 + l16;
        #pragma unroll
        for (int r = 0; r < 4; r++)
            G[(size_t)(m0 + w * 16 + quad * 4 + r) * 1536 + gj] = acc[r] + bv_;
    }
}

__device__ __forceinline__ float gru1(float ir, float iz, float in_,
                                      float hr, float hz, float hn, float hp) {
    float r = 1.0f / (1.0f + __expf(-(ir + hr)));
    float z = 1.0f / (1.0f + __expf(-(iz + hz)));
    float n = tanhf(in_ + r * hn);
    return (1.0f - z) * n + z * hp;
}

// ---------------- k_gru2: GRU elementwise + post-LN + MLP1 + MLP2, fused.
// 16 blocks x 16 rows. Split-bf16 MFMA for both MLP GEMMs (~f32 precision).
__global__ __launch_bounds__(256) void k_gru2(
    const float* __restrict__ slots, const float* __restrict__ G,
    const unsigned short* __restrict__ W1Th, const unsigned short* __restrict__ W1Tl,
    const float* __restrict__ b1,
    const unsigned short* __restrict__ W2Th, const unsigned short* __restrict__ W2Tl,
    const float* __restrict__ b2,
    const float* __restrict__ g_post, const float* __restrict__ b_post,
    float* __restrict__ out)
{
    int r0 = blockIdx.x * 16, t = threadIdx.x;
    __shared__ __align__(16) unsigned short lnH[16][264], lnLo[16][264];
    __shared__ __align__(16) float hnL[16][260];
    __shared__ __align__(16) unsigned short y1H[16][520], y1Lo[16][520];

    // phase 1: GRU + LN for rows r0..r0+15 (thread: row t>>4, 16 cols)
    int rr = t >> 4, c0 = (t & 15) * 16;
    int grow = r0 + rr;
    float hnew[16];
    float ssum = 0.0f, ssq = 0.0f;
    #pragma unroll
    for (int i = 0; i < 4; i++) {
        int c = c0 + i * 4;
        const float* gp = &G[(size_t)grow * 1536 + c];
        float4 gir = *(const float4*)(gp);
        float4 giz = *(const float4*)(gp + 256);
        float4 gin = *(const float4*)(gp + 512);
        float4 ghr = *(const float4*)(gp + 768);
        float4 ghz = *(const float4*)(gp + 1024);
        float4 ghn = *(const float4*)(gp + 1280);
        float4 hp  = *(const float4*)&slots[(size_t)grow * 256 + c];
        float h0 = gru1(gir.x, giz.x, gin.x, ghr.x, ghz.x, ghn.x, hp.x);
        float h1 = gru1(gir.y, giz.y, gin.y, ghr.y, ghz.y, ghn.y, hp.y);
        float h2 = gru1(gir.z, giz.z, gin.z, ghr.z, ghz.z, ghn.z, hp.z);
        float h3 = gru1(gir.w, giz.w, gin.w, ghr.w, ghz.w, ghn.w, hp.w);
        hnew[i * 4 + 0] = h0; hnew[i * 4 + 1] = h1;
        hnew[i * 4 + 2] = h2; hnew[i * 4 + 3] = h3;
        ssum += h0 + h1 + h2 + h3;
        ssq  += h0 * h0 + h1 * h1 + h2 * h2 + h3 * h3;
    }
    #pragma unroll
    for (int m = 1; m <= 8; m <<= 1) {
        ssum += __shfl_xor(ssum, m, 64);
        ssq  += __shfl_xor(ssq, m, 64);
    }
    float mu = ssum * (1.0f / 256);
    float var = ssq * (1.0f / 256) - mu * mu;
    float rstd = rsqrtf(var + 1e-5f);
    #pragma unroll
    for (int i = 0; i < 4; i++) {
        int c = c0 + i * 4;
        float4 gp4 = *(const float4*)&g_post[c];
        float4 bp4 = *(const float4*)&b_post[c];
        float l0 = (hnew[i*4+0] - mu) * rstd * gp4.x + bp4.x;
        float l1 = (hnew[i*4+1] - mu) * rstd * gp4.y + bp4.y;
        float l2 = (hnew[i*4+2] - mu) * rstd * gp4.z + bp4.z;
        float l3 = (hnew[i*4+3] - mu) * rstd * gp4.w + bp4.w;
        unsigned short h0,lo0,h1,lo1,h2,lo2,h3,lo3;
        split2(l0, h0, lo0); split2(l1, h1, lo1);
        split2(l2, h2, lo2); split2(l3, h3, lo3);
        *(v4s*)&lnH[rr][c]  = (v4s){(short)h0,(short)h1,(short)h2,(short)h3};
        *(v4s*)&lnLo[rr][c] = (v4s){(short)lo0,(short)lo1,(short)lo2,(short)lo3};
        float4 hv4; hv4.x = hnew[i*4+0]; hv4.y = hnew[i*4+1];
        hv4.z = hnew[i*4+2]; hv4.w = hnew[i*4+3];
        *(float4*)&hnL[rr][c] = hv4;
    }
    __syncthreads();

    int w = t >> 6, lane = t & 63, quad = lane >> 4, l16 = lane & 15;
    // phase 2: y1[16][512] = relu(ln @ W1 + b1); wave owns 128 cols
    for (int s = 0; s < 8; s++) {
        int n = w * 128 + s * 16 + l16;
        v4f acc = (v4f){0.f, 0.f, 0.f, 0.f};
        #pragma unroll
        for (int kk = 0; kk < 8; kk++) {
            v8s ah = *(const v8s*)&lnH[l16][kk * 32 + quad * 8];
            v8s al = *(const v8s*)&lnLo[l16][kk * 32 + quad * 8];
            v8s bh = *(const v8s*)&W1Th[(size_t)n * 256 + kk * 32 + quad * 8];
            v8s bl = *(const v8s*)&W1Tl[(size_t)n * 256 + kk * 32 + quad * 8];
            acc = __builtin_amdgcn_mfma_f32_16x16x32_bf16(al, bh, acc, 0, 0, 0);
            acc = __builtin_amdgcn_mfma_f32_16x16x32_bf16(ah, bl, acc, 0, 0, 0);
            acc = __builtin_amdgcn_mfma_f32_16x16x32_bf16(ah, bh, acc, 0, 0, 0);
        }
        float bb = b1[n];
        #pragma unroll
        for (int r = 0; r < 4; r++) {
            float y = fmaxf(acc[r] + bb, 0.0f);
            unsigned short hi, lo; split2(y, hi, lo);
            y1H[quad * 4 + r][n]  = hi;
            y1Lo[quad * 4 + r][n] = lo;
        }
    }
    __syncthreads();

    // phase 3: out[16][256] = hnew + y1 @ W2 + b2; wave owns 64 cols
    for (int s = 0; s < 4; s++) {
        int n = w * 64 + s * 16 + l16;
        v4f acc = (v4f){0.f, 0.f, 0.f, 0.f};
        #pragma unroll
        for (int kk = 0; kk < 16; kk++) {
            v8s ah = *(const v8s*)&y1H[l16][kk * 32 + quad * 8];
            v8s al = *(const v8s*)&y1Lo[l16][kk * 32 + quad * 8];
            v8s bh = *(const v8s*)&W2Th[(size_t)n * 512 + kk * 32 + quad * 8];
            v8s bl = *(const v8s*)&W2Tl[(size_t)n * 512 + kk * 32 + quad * 8];
            acc = __builtin_amdgcn_mfma_f32_16x16x32_bf16(al, bh, acc, 0, 0, 0);
            acc = __builtin_amdgcn_mfma_f32_16x16x32_bf16(ah, bl, acc, 0, 0, 0);
            acc = __builtin_amdgcn_mfma_f32_16x16x32_bf16(ah, bh, acc, 0, 0, 0);
        }
        float bb = b2[n];
        #pragma unroll
        for (int r = 0; r < 4; r++) {
            int m = quad * 4 + r;
            out[(size_t)(r0 + m) * 256 + n] = hnL[m][n] + acc[r] + bb;
        }
    }
}

extern "C" void kernel_launch(void* const* d_in, const int* in_sizes, int n_in,
                              void* d_out, int out_size, void* d_ws, size_t ws_size,
                              hipStream_t stream) {
    const float* features = (const float*)d_in[0];
    const float* slots    = (const float*)d_in[1];
    const float* Wq   = (const float*)d_in[2];
    const float* bq   = (const float*)d_in[3];
    const float* Wk   = (const float*)d_in[4];
    const float* bk   = (const float*)d_in[5];
    const float* Wv   = (const float*)d_in[6];
    const float* bv   = (const float*)d_in[7];
    const float* W_ih = (const float*)d_in[8];
    const float* b_ih = (const float*)d_in[9];
    const float* W_hh = (const float*)d_in[10];
    const float* b_hh = (const float*)d_in[11];
    const float* g_pre  = (const float*)d_in[12];
    const float* b_pre  = (const float*)d_in[13];
    const float* g_post = (const float*)d_in[14];
    const float* b_post = (const float*)d_in[15];
    const float* W1 = (const float*)d_in[16];
    const float* b1 = (const float*)d_in[17];
    const float* W2 = (const float*)d_in[18];
    const float* b2 = (const float*)d_in[19];
    float* out = (float*)d_out;

    // ws layout (2.5 MB): G f32 [0,1.5MB) — ALIASES qkT/qb, which are dead
    // after k_attn (kernels are stream-ordered). W1T/W2T hi/lo follow.
    char* wsb = (char*)d_ws;
    float* G               = (float*)wsb;                          // 1572864 B
    unsigned short* qkT_ws = (unsigned short*)wsb;                 // 262144 B (sub-region of G)
    float* qb_ws           = (float*)(wsb + 262144);               // 4096 B  (sub-region of G)
    unsigned short* W1Th   = (unsigned short*)(wsb + 1572864);     // 262144 B
    unsigned short* W1Tl   = (unsigned short*)(wsb + 1835008);     // 262144 B
    unsigned short* W2Th   = (unsigned short*)(wsb + 2097152);     // 262144 B
    unsigned short* W2Tl   = (unsigned short*)(wsb + 2359296);     // 262144 B
    float* agg_ws = out;   // agg accumulator in d_out (zeroed by k_prep chunk0)

    k_prep<<<dim3(256), dim3(256), 0, stream>>>(slots, Wq, bq, g_pre, b_pre,
                                                Wk, bk, qkT_ws, qb_ws, agg_ws);
    k_wconv<<<dim3(256), dim3(256), 0, stream>>>(W1, W2, W1Th, W1Tl, W2Th, W2Tl);
    k_attn<<<dim3(32, 32), dim3(256), 0, stream>>>(features, Wv, bv, qkT_ws, qb_ws, agg_ws);
    k_gate<<<dim3(24, 4), dim3(256), 0, stream>>>(agg_ws, slots, W_ih, b_ih,
                                                  W_hh, b_hh, G);
    k_gru2<<<dim3(16), dim3(256), 0, stream>>>(slots, G, W1Th, W1Tl, b1,
                                               W2Th, W2Tl, b2, g_post, b_post, out);
}

// Round 12
// 211.654 us; speedup vs baseline: 4.3216x; 1.0033x over previous
//
#include <hip/hip_runtime.h>
#include <hip/hip_bf16.h>

#define NSLOT 8
#define SDIM 256
#define FDIM 128
#define NHEAD 4
#define HDIM 64
#define NPOS 4096

typedef short v8s __attribute__((ext_vector_type(8)));
typedef short v4s __attribute__((ext_vector_type(4)));
typedef float v4f __attribute__((ext_vector_type(4)));

__device__ __forceinline__ unsigned short f2bf(float x) {
    __hip_bfloat16 h = __float2bfloat16(x);
    unsigned short u; __builtin_memcpy(&u, &h, 2); return u;
}
__device__ __forceinline__ float bfr2f(unsigned short u) {
    __hip_bfloat16 h; __builtin_memcpy(&h, &u, 2); return __bfloat162float(h);
}
__device__ __forceinline__ void split2(float x, unsigned short& hi, unsigned short& lo) {
    hi = f2bf(x);
    lo = f2bf(x - bfr2f(hi));
}

// ---------------- K1 (fused prep, 592 blocks):
//   blk   0..255: per-batch LN(slots)+q+qkT/qb, zero agg (b=blk>>3, chunk=blk&7)
//   blk 256..511: W1 (256x512) / W2 (512x256) transpose -> hi/lo bf16 [n][k]
//   blk 512..559: W_ih / W_hh (768x256 EACH) elementwise split -> hi/lo bf16
//   blk 560..591: Wv (128x256) transpose -> WvT hi/lo bf16 [256][128]
__global__ __launch_bounds__(256) void k_prep(
    const float* __restrict__ slots,
    const float* __restrict__ Wq, const float* __restrict__ bq,
    const float* __restrict__ g_pre, const float* __restrict__ b_pre,
    const float* __restrict__ Wk, const float* __restrict__ bk,
    const float* __restrict__ W1, const float* __restrict__ W2,
    const float* __restrict__ W_ih, const float* __restrict__ W_hh,
    const float* __restrict__ Wv,
    unsigned short* __restrict__ qkT_ws, float* __restrict__ qb_ws,
    unsigned short* __restrict__ W1Th, unsigned short* __restrict__ W1Tl,
    unsigned short* __restrict__ W2Th, unsigned short* __restrict__ W2Tl,
    unsigned short* __restrict__ WihH, unsigned short* __restrict__ WihL,
    unsigned short* __restrict__ WhhH, unsigned short* __restrict__ WhhL,
    unsigned short* __restrict__ WvTH, unsigned short* __restrict__ WvTl,
    float* __restrict__ agg_ws)
{
    int blk = blockIdx.x, t = threadIdx.x;
    __shared__ float s_ln[8 * 256];
    __shared__ float q_l[32 * 65];   // stride 65: conflict-free
    __shared__ float red1[256], red2[256];
    __shared__ float tl[32][33];

    if (blk >= 560) {                // WvT transpose+split (32 blocks)
        int id3 = blk - 560;
        int k0 = (id3 & 3) * 32, n0 = (id3 >> 2) * 32;
        for (int i = 0; i < 4; i++) {
            int idx = i * 256 + t, r = idx >> 5, c = idx & 31;
            tl[r][c] = Wv[(size_t)(k0 + r) * 256 + n0 + c];
        }
        __syncthreads();
        for (int i = 0; i < 4; i++) {
            int idx = i * 256 + t, r = idx >> 5, c = idx & 31;
            unsigned short hi, lo; split2(tl[c][r], hi, lo);
            WvTH[(size_t)(n0 + r) * 128 + k0 + c] = hi;
            WvTl[(size_t)(n0 + r) * 128 + k0 + c] = lo;
        }
        return;
    }
    if (blk >= 512) {                // gate-weight split: 768 rows EACH (24 blocks each)
        int id2 = blk - 512;         // 0..47
        const float* src; unsigned short *dh, *dl; int r0;
        if (id2 < 24) { src = W_ih; dh = WihH; dl = WihL; r0 = id2 * 32; }
        else          { src = W_hh; dh = WhhH; dl = WhhL; r0 = (id2 - 24) * 32; }
        for (int i = 0; i < 32; i++) {
            size_t idx = (size_t)(r0 + i) * 256 + t;   // max (767)*256+255 < 768*256
            unsigned short hi, lo; split2(src[idx], hi, lo);
            dh[idx] = hi; dl[idx] = lo;
        }
        return;
    }
    if (blk >= 256) {                // W1/W2 transpose+split
        int id = blk - 256;
        const float* src; unsigned short *dh, *dl; int N, K, k0, n0;
        if (id < 128) { src = W1; dh = W1Th; dl = W1Tl; N = 512; K = 256;
                        k0 = (id >> 4) * 32; n0 = (id & 15) * 32; }
        else          { int i2 = id - 128; src = W2; dh = W2Th; dl = W2Tl; N = 256; K = 512;
                        k0 = (i2 >> 3) * 32; n0 = (i2 & 7) * 32; }
        for (int i = 0; i < 4; i++) {
            int idx = i * 256 + t, r = idx >> 5, c = idx & 31;
            tl[r][c] = src[(size_t)(k0 + r) * N + n0 + c];
        }
        __syncthreads();
        for (int i = 0; i < 4; i++) {
            int idx = i * 256 + t, r = idx >> 5, c = idx & 31;
            unsigned short hi, lo; split2(tl[c][r], hi, lo);
            dh[(size_t)(n0 + r) * K + k0 + c] = hi;
            dl[(size_t)(n0 + r) * K + k0 + c] = lo;
        }
        return;
    }

    // ---- per-batch prep ----
    int b = blk >> 3, chunk = blk & 7;
    if (chunk == 0)
        for (int i = 0; i < 8; i++) agg_ws[b * 2048 + i * 256 + t] = 0.0f;

    int s8 = t >> 5, lane = t & 31;
    float xv[8], sum = 0.0f, sq = 0.0f;
    for (int u = 0; u < 8; u++) {
        float x = slots[(b * 8 + s8) * 256 + lane * 8 + u];
        xv[u] = x; sum += x; sq += x * x;
    }
    red1[t] = sum; red2[t] = sq;
    __syncthreads();
    for (int o = 16; o > 0; o >>= 1) {
        if (lane < o) { red1[t] += red1[t + o]; red2[t] += red2[t + o]; }
        __syncthreads();
    }
    float mu  = red1[s8 * 32] * (1.0f / 256);
    float var = red2[s8 * 32] * (1.0f / 256) - mu * mu;
    float rstd = rsqrtf(var + 1e-5f);
    for (int u = 0; u < 8; u++) {
        int j = lane * 8 + u;
        s_ln[s8 * 256 + j] = (xv[u] - mu) * rstd * g_pre[j] + b_pre[j];
    }
    __syncthreads();

    float qa[8];
    #pragma unroll
    for (int s = 0; s < 8; s++) qa[s] = bq[t];
    for (int k = 0; k < 256; k++) {
        float wq = Wq[k * 256 + t];
        #pragma unroll
        for (int s = 0; s < 8; s++) qa[s] += s_ln[s * 256 + k] * wq;
    }
    int h = t >> 6, d = t & 63;
    for (int s = 0; s < 8; s++) q_l[(s * 4 + h) * 65 + d] = qa[s];
    __syncthreads();

    int hs = t & 31, hh = hs >> 3, si = hs & 7, c0 = t >> 5;
    const float* qrow = &q_l[(si * 4 + hh) * 65];
    for (int i = 0; i < 2; i++) {
        int c = chunk * 16 + i * 8 + c0;
        const float4* wk4 = (const float4*)&Wk[c * 256 + hh * 64];
        float acc = 0.0f;
        #pragma unroll
        for (int d4 = 0; d4 < 16; d4++) {
            float4 w = wk4[d4];
            acc += w.x * qrow[d4 * 4] + w.y * qrow[d4 * 4 + 1]
                 + w.z * qrow[d4 * 4 + 2] + w.w * qrow[d4 * 4 + 3];
        }
        qkT_ws[(b * 32 + hs) * 128 + c] = f2bf(acc);
    }
    if (chunk == 0 && t < 32) {
        int h2 = t >> 3, s2 = t & 7;
        float acc = 0.0f;
        for (int d2 = 0; d2 < 64; d2++)
            acc += bk[h2 * 64 + d2] * q_l[(s2 * 4 + h2) * 65 + d2];
        qb_ws[b * 32 + t] = acc;
    }
}

// ---------------- K2: MFMA scores + softmax + MFMA attF^T + MFMA epilogue --
// LDS (31360 B): featPC bf16 [32][136] @0; featCP bf16 [128][56] @8704;
// s_attn f32 [32][36] @23040; s_aT bf16 [32][56] @27648; s_S f32[32] @31232.
// After the tile loop, featPC/featCP are dead and alias attFH/attFL bf16
// [32][136] (hi/lo split of the f32 attF accumulator).
__global__ __launch_bounds__(256, 4) void k_attn(
    const float* __restrict__ feat,   // (B,128,4096)
    const unsigned short* __restrict__ WvTH, const unsigned short* __restrict__ WvTl,
    const float* __restrict__ bv,
    const unsigned short* __restrict__ qkT, const float* __restrict__ qb_ws,
    float* __restrict__ agg_ws)
{
    __shared__ __align__(16) char smem[31360];
    unsigned short* featPC = (unsigned short*)smem;              // stride 136
    unsigned short* featCP = (unsigned short*)(smem + 8704);     // stride 56
    unsigned short* attFH  = (unsigned short*)smem;              // alias, stride 136
    unsigned short* attFL  = (unsigned short*)(smem + 8704);     // alias, stride 136
    float*          s_attn = (float*)(smem + 23040);             // stride 36
    unsigned short* s_aT   = (unsigned short*)(smem + 27648);    // stride 56
    float*          s_S    = (float*)(smem + 31232);

    int t = threadIdx.x, b = blockIdx.y, n0 = blockIdx.x * 128;
    int wv_ = t >> 6, lane = t & 63, quad = lane >> 4, l16 = lane & 15;
    int mt = wv_ >> 1, nt = wv_ & 1;
    int sp  = l16 + mt * 16;
    int shs = l16 + nt * 16;

    v8s bq_[4];
    #pragma unroll
    for (int ch = 0; ch < 4; ch++)
        bq_[ch] = *(const v8s*)&qkT[(b * 32 + shs) * 128 + ch * 32 + quad * 8];
    float qbv = qb_ws[b * 32 + shs];
    if (t < 32) s_S[t] = 0.0f;

    v4f accF[4];
    #pragma unroll
    for (int i = 0; i < 4; i++) accF[i] = (v4f){0.f, 0.f, 0.f, 0.f};

    int c0 = (t >> 3) * 4, p0 = (t & 7) * 4;

    for (int tt = 0; tt < 4; ++tt) {
        __syncthreads();
        int nb = n0 + tt * 32;
        float fv[4][4];
        #pragma unroll
        for (int r = 0; r < 4; r++) {
            float4 f = *(const float4*)&feat[(size_t)b * (FDIM * NPOS)
                                             + (size_t)(c0 + r) * NPOS + nb + p0];
            fv[r][0] = f.x; fv[r][1] = f.y; fv[r][2] = f.z; fv[r][3] = f.w;
        }
        #pragma unroll
        for (int r = 0; r < 4; r++)
            *(v4s*)&featCP[(c0 + r) * 56 + p0] =
                (v4s){(short)f2bf(fv[r][0]), (short)f2bf(fv[r][1]),
                      (short)f2bf(fv[r][2]), (short)f2bf(fv[r][3])};
        #pragma unroll
        for (int j = 0; j < 4; j++)
            *(v4s*)&featPC[(p0 + j) * 136 + c0] =
                (v4s){(short)f2bf(fv[0][j]), (short)f2bf(fv[1][j]),
                      (short)f2bf(fv[2][j]), (short)f2bf(fv[3][j])};
        __syncthreads();

        v4f acc = (v4f){0.f, 0.f, 0.f, 0.f};
        #pragma unroll
        for (int ch = 0; ch < 4; ch++) {
            v8s a = *(const v8s*)&featPC[sp * 136 + ch * 32 + quad * 8];
            acc = __builtin_amdgcn_mfma_f32_16x16x32_bf16(a, bq_[ch], acc, 0, 0, 0);
        }
        int pb = mt * 16 + quad * 4;
        #pragma unroll
        for (int r = 0; r < 4; r++)
            s_attn[(pb + r) * 36 + shs] = (acc[r] + qbv) * 0.125f;
        __syncthreads();

        if (t < 128) {
            int p = t >> 2, h2 = t & 3;
            float* a = &s_attn[p * 36 + h2 * 8];
            float m = a[0];
            for (int s = 1; s < 8; s++) m = fmaxf(m, a[s]);
            float e[8], ssum = 0.0f;
            for (int s = 0; s < 8; s++) { e[s] = __expf(a[s] - m); ssum += e[s]; }
            float inv = 1.0f / ssum;
            for (int s = 0; s < 8; s++)
                s_aT[(h2 * 8 + s) * 56 + p] = f2bf(e[s] * inv);
        }
        __syncthreads();

        v8s aA0 = *(const v8s*)&s_aT[l16 * 56 + quad * 8];
        v8s aA1 = *(const v8s*)&s_aT[(l16 + 16) * 56 + quad * 8];
        v8s bF0 = *(const v8s*)&featCP[(l16 + wv_ * 32) * 56 + quad * 8];
        v8s bF1 = *(const v8s*)&featCP[(l16 + wv_ * 32 + 16) * 56 + quad * 8];
        accF[0] = __builtin_amdgcn_mfma_f32_16x16x32_bf16(aA0, bF0, accF[0], 0, 0, 0);
        accF[1] = __builtin_amdgcn_mfma_f32_16x16x32_bf16(aA0, bF1, accF[1], 0, 0, 0);
        accF[2] = __builtin_amdgcn_mfma_f32_16x16x32_bf16(aA1, bF0, accF[2], 0, 0, 0);
        accF[3] = __builtin_amdgcn_mfma_f32_16x16x32_bf16(aA1, bF1, accF[3], 0, 0, 0);
        if (t < 32) {
            float ss = 0.0f;
            for (int p = 0; p < 32; p++) ss += bfr2f(s_aT[t * 56 + p]);
            s_S[t] += ss;
        }
    }
    __syncthreads();                 // feats views dead; alias as attFH/attFL
    #pragma unroll
    for (int mt2 = 0; mt2 < 2; mt2++)
        #pragma unroll
        for (int ntl = 0; ntl < 2; ntl++) {
            v4f f = accF[mt2 * 2 + ntl];
            int cc = wv_ * 32 + ntl * 16 + l16;
            #pragma unroll
            for (int r = 0; r < 4; r++) {
                unsigned short hi, lo; split2(f[r], hi, lo);
                attFH[(mt2 * 16 + quad * 4 + r) * 136 + cc] = hi;
                attFL[(mt2 * 16 + quad * 4 + r) * 136 + cc] = lo;
            }
        }
    __syncthreads();

    // epilogue GEMM per head (wave = head): agg[s][d] = sum_c attF[h8+s][c]*WvT[d][c]
    // M=8 (A rows duplicated to 16 via l16&7; D rows 8..15 are dupes -> masked)
    int h = wv_;
    int am = h * 8 + (l16 & 7);
    for (int nt2 = 0; nt2 < 4; nt2++) {
        int n = h * 64 + nt2 * 16 + l16;     // output dim d
        v4f acc = (v4f){0.f, 0.f, 0.f, 0.f};
        #pragma unroll
        for (int kk = 0; kk < 4; kk++) {
            int ko = kk * 32 + quad * 8;
            v8s ah = *(const v8s*)&attFH[am * 136 + ko];
            v8s al = *(const v8s*)&attFL[am * 136 + ko];
            v8s bh = *(const v8s*)&WvTH[(size_t)n * 128 + ko];
            v8s bl = *(const v8s*)&WvTl[(size_t)n * 128 + ko];
            acc = __builtin_amdgcn_mfma_f32_16x16x32_bf16(al, bh, acc, 0, 0, 0);
            acc = __builtin_amdgcn_mfma_f32_16x16x32_bf16(ah, bl, acc, 0, 0, 0);
            acc = __builtin_amdgcn_mfma_f32_16x16x32_bf16(ah, bh, acc, 0, 0, 0);
        }
        float bvn = bv[n];
        if (quad < 2) {
            #pragma unroll
            for (int r = 0; r < 4; r++) {
                int s = quad * 4 + r;
                atomicAdd(&agg_ws[b * 2048 + s * 256 + n],
                          acc[r] + s_S[h * 8 + s] * bvn);
            }
        }
    }
}

// ---------------- K3: G[256][1536] = [x@W_ih^T + b_ih | h@W_hh^T + b_hh]
// Split-bf16 MFMA; B hi/lo PRECOMPUTED (768 rows each).
__global__ __launch_bounds__(256) void k_gate(
    const float* __restrict__ agg, const float* __restrict__ slots,
    const unsigned short* __restrict__ WihH, const unsigned short* __restrict__ WihL,
    const float* __restrict__ b_ih,
    const unsigned short* __restrict__ WhhH, const unsigned short* __restrict__ WhhL,
    const float* __restrict__ b_hh,
    float* __restrict__ G)
{
    int ntile = blockIdx.x, mtile = blockIdx.y, t = threadIdx.x;
    bool hhalf = ntile >= 12;
    int jbase = (hhalf ? ntile - 12 : ntile) * 64;
    const float* X = hhalf ? slots : agg;
    const unsigned short* BH = hhalf ? WhhH : WihH;
    const unsigned short* BL = hhalf ? WhhL : WihL;
    const float* bias = hhalf ? b_hh : b_ih;
    int gofs = hhalf ? 768 : 0;
    int m0 = mtile * 64;

    __shared__ __align__(16) unsigned short aH[64][264];
    __shared__ __align__(16) unsigned short aL[64][264];
    for (int i = 0; i < 16; i++) {
        int idx = i * 256 + t;
        int r = idx >> 6, q = idx & 63;
        float4 f = *(const float4*)&X[(size_t)(m0 + r) * 256 + q * 4];
        unsigned short h0,l0,h1,l1,h2,l2,h3,l3;
        split2(f.x, h0, l0); split2(f.y, h1, l1);
        split2(f.z, h2, l2); split2(f.w, h3, l3);
        *(v4s*)&aH[r][q * 4] = (v4s){(short)h0,(short)h1,(short)h2,(short)h3};
        *(v4s*)&aL[r][q * 4] = (v4s){(short)l0,(short)l1,(short)l2,(short)l3};
    }
    __syncthreads();

    int w = t >> 6, lane = t & 63, quad = lane >> 4, l16 = lane & 15;
    int am = w * 16 + l16;
    for (int s = 0; s < 4; s++) {
        int jrow = jbase + s * 16 + l16;     // 0..767
        v4f acc = (v4f){0.f, 0.f, 0.f, 0.f};
        #pragma unroll
        for (int kk = 0; kk < 8; kk++) {
            int ko = kk * 32 + quad * 8;
            v8s ah = *(const v8s*)&aH[am][ko];
            v8s al = *(const v8s*)&aL[am][ko];
            v8s bh = *(const v8s*)&BH[(size_t)jrow * 256 + ko];
            v8s bl = *(const v8s*)&BL[(size_t)jrow * 256 + ko];
            acc = __builtin_amdgcn_mfma_f32_16x16x32_bf16(al, bh, acc, 0, 0, 0);
            acc = __builtin_amdgcn_mfma_f32_16x16x32_bf16(ah, bl, acc, 0, 0, 0);
            acc = __builtin_amdgcn_mfma_f32_16x16x32_bf16(ah, bh, acc, 0, 0, 0);
        }
        float bv_ = bias[jrow];
        int gj = gofs + jbase + s * 16 + l16;
        #pragma unroll
        for (int r = 0; r < 4; r++)
            G[(size_t)(m0 + w * 16 + quad * 4 + r) * 1536 + gj] = acc[r] + bv_;
    }
}

__device__ __forceinline__ float gru1(float ir, float iz, float in_,
                                      float hr, float hz, float hn, float hp) {
    float r = 1.0f / (1.0f + __expf(-(ir + hr)));
    float z = 1.0f / (1.0f + __expf(-(iz + hz)));
    float n = tanhf(in_ + r * hn);
    return (1.0f - z) * n + z * hp;
}

// ---------------- K4: GRU elementwise + post-LN + MLP1 + MLP2, fused -------
__global__ __launch_bounds__(256) void k_gru2(
    const float* __restrict__ slots, const float* __restrict__ G,
    const unsigned short* __restrict__ W1Th, const unsigned short* __restrict__ W1Tl,
    const float* __restrict__ b1,
    const unsigned short* __restrict__ W2Th, const unsigned short* __restrict__ W2Tl,
    const float* __restrict__ b2,
    const float* __restrict__ g_post, const float* __restrict__ b_post,
    float* __restrict__ out)
{
    int r0 = blockIdx.x * 16, t = threadIdx.x;
    __shared__ __align__(16) unsigned short lnH[16][264], lnLo[16][264];
    __shared__ __align__(16) float hnL[16][260];
    __shared__ __align__(16) unsigned short y1H[16][520], y1Lo[16][520];

    int rr = t >> 4, c0 = (t & 15) * 16;
    int grow = r0 + rr;
    float hnew[16];
    float ssum = 0.0f, ssq = 0.0f;
    #pragma unroll
    for (int i = 0; i < 4; i++) {
        int c = c0 + i * 4;
        const float* gp = &G[(size_t)grow * 1536 + c];
        float4 gir = *(const float4*)(gp);
        float4 giz = *(const float4*)(gp + 256);
        float4 gin = *(const float4*)(gp + 512);
        float4 ghr = *(const float4*)(gp + 768);
        float4 ghz = *(const float4*)(gp + 1024);
        float4 ghn = *(const float4*)(gp + 1280);
        float4 hp  = *(const float4*)&slots[(size_t)grow * 256 + c];
        float h0 = gru1(gir.x, giz.x, gin.x, ghr.x, ghz.x, ghn.x, hp.x);
        float h1 = gru1(gir.y, giz.y, gin.y, ghr.y, ghz.y, ghn.y, hp.y);
        float h2 = gru1(gir.z, giz.z, gin.z, ghr.z, ghz.z, ghn.z, hp.z);
        float h3 = gru1(gir.w, giz.w, gin.w, ghr.w, ghz.w, ghn.w, hp.w);
        hnew[i * 4 + 0] = h0; hnew[i * 4 + 1] = h1;
        hnew[i * 4 + 2] = h2; hnew[i * 4 + 3] = h3;
        ssum += h0 + h1 + h2 + h3;
        ssq  += h0 * h0 + h1 * h1 + h2 * h2 + h3 * h3;
    }
    #pragma unroll
    for (int m = 1; m <= 8; m <<= 1) {
        ssum += __shfl_xor(ssum, m, 64);
        ssq  += __shfl_xor(ssq, m, 64);
    }
    float mu = ssum * (1.0f / 256);
    float var = ssq * (1.0f / 256) - mu * mu;
    float rstd = rsqrtf(var + 1e-5f);
    #pragma unroll
    for (int i = 0; i < 4; i++) {
        int c = c0 + i * 4;
        float4 gp4 = *(const float4*)&g_post[c];
        float4 bp4 = *(const float4*)&b_post[c];
        float l0 = (hnew[i*4+0] - mu) * rstd * gp4.x + bp4.x;
        float l1 = (hnew[i*4+1] - mu) * rstd * gp4.y + bp4.y;
        float l2 = (hnew[i*4+2] - mu) * rstd * gp4.z + bp4.z;
        float l3 = (hnew[i*4+3] - mu) * rstd * gp4.w + bp4.w;
        unsigned short h0,lo0,h1,lo1,h2,lo2,h3,lo3;
        split2(l0, h0, lo0); split2(l1, h1, lo1);
        split2(l2, h2, lo2); split2(l3, h3, lo3);
        *(v4s*)&lnH[rr][c]  = (v4s){(short)h0,(short)h1,(short)h2,(short)h3};
        *(v4s*)&lnLo[rr][c] = (v4s){(short)lo0,(short)lo1,(short)lo2,(short)lo3};
        float4 hv4; hv4.x = hnew[i*4+0]; hv4.y = hnew[i*4+1];
        hv4.z = hnew[i*4+2]; hv4.w = hnew[i*4+3];
        *(float4*)&hnL[rr][c] = hv4;
    }
    __syncthreads();

    int w = t >> 6, lane = t & 63, quad = lane >> 4, l16 = lane & 15;
    for (int s = 0; s < 8; s++) {
        int n = w * 128 + s * 16 + l16;
        v4f acc = (v4f){0.f, 0.f, 0.f, 0.f};
        #pragma unroll
        for (int kk = 0; kk < 8; kk++) {
            int ko = kk * 32 + quad * 8;
            v8s ah = *(const v8s*)&lnH[l16][ko];
            v8s al = *(const v8s*)&lnLo[l16][ko];
            v8s bh = *(const v8s*)&W1Th[(size_t)n * 256 + ko];
            v8s bl = *(const v8s*)&W1Tl[(size_t)n * 256 + ko];
            acc = __builtin_amdgcn_mfma_f32_16x16x32_bf16(al, bh, acc, 0, 0, 0);
            acc = __builtin_amdgcn_mfma_f32_16x16x32_bf16(ah, bl, acc, 0, 0, 0);
            acc = __builtin_amdgcn_mfma_f32_16x16x32_bf16(ah, bh, acc, 0, 0, 0);
        }
        float bb = b1[n];
        #pragma unroll
        for (int r = 0; r < 4; r++) {
            float y = fmaxf(acc[r] + bb, 0.0f);
            unsigned short hi, lo; split2(y, hi, lo);
            y1H[quad * 4 + r][n]  = hi;
            y1Lo[quad * 4 + r][n] = lo;
        }
    }
    __syncthreads();

    for (int s = 0; s < 4; s++) {
        int n = w * 64 + s * 16 + l16;
        v4f acc = (v4f){0.f, 0.f, 0.f, 0.f};
        #pragma unroll
        for (int kk = 0; kk < 16; kk++) {
            int ko = kk * 32 + quad * 8;
            v8s ah = *(const v8s*)&y1H[l16][ko];
            v8s al = *(const v8s*)&y1Lo[l16][ko];
            v8s bh = *(const v8s*)&W2Th[(size_t)n * 512 + ko];
            v8s bl = *(const v8s*)&W2Tl[(size_t)n * 512 + ko];
            acc = __builtin_amdgcn_mfma_f32_16x16x32_bf16(al, bh, acc, 0, 0, 0);
            acc = __builtin_amdgcn_mfma_f32_16x16x32_bf16(ah, bl, acc, 0, 0, 0);
            acc = __builtin_amdgcn_mfma_f32_16x16x32_bf16(ah, bh, acc, 0, 0, 0);
        }
        float bb = b2[n];
        #pragma unroll
        for (int r = 0; r < 4; r++) {
            int m = quad * 4 + r;
            out[(size_t)(r0 + m) * 256 + n] = hnL[m][n] + acc[r] + bb;
        }
    }
}

extern "C" void kernel_launch(void* const* d_in, const int* in_sizes, int n_in,
                              void* d_out, int out_size, void* d_ws, size_t ws_size,
                              hipStream_t stream) {
    const float* features = (const float*)d_in[0];
    const float* slots    = (const float*)d_in[1];
    const float* Wq   = (const float*)d_in[2];
    const float* bq   = (const float*)d_in[3];
    const float* Wk   = (const float*)d_in[4];
    const float* bk   = (const float*)d_in[5];
    const float* Wv   = (const float*)d_in[6];
    const float* bv   = (const float*)d_in[7];
    const float* W_ih = (const float*)d_in[8];
    const float* b_ih = (const float*)d_in[9];
    const float* W_hh = (const float*)d_in[10];
    const float* b_hh = (const float*)d_in[11];
    const float* g_pre  = (const float*)d_in[12];
    const float* b_pre  = (const float*)d_in[13];
    const float* g_post = (const float*)d_in[14];
    const float* b_post = (const float*)d_in[15];
    const float* W1 = (const float*)d_in[16];
    const float* b1 = (const float*)d_in[17];
    const float* W2 = (const float*)d_in[18];
    const float* b2 = (const float*)d_in[19];
    float* out = (float*)d_out;

    // ws layout (4.125 MB total; ws is 256 MB per round-10 fill counters):
    //   G f32 [0,1.5MB)   — aliases qkT 256KB + qb 4KB (dead after k_attn)
    //   W1T/W2T hi/lo 4x256KB | Wih/Whh hi/lo 4x384KB | WvT hi/lo 2x64KB
    char* wsb = (char*)d_ws;
    float* G               = (float*)wsb;
    unsigned short* qkT_ws = (unsigned short*)wsb;
    float* qb_ws           = (float*)(wsb + 262144);
    unsigned short* W1Th   = (unsigned short*)(wsb + 1572864);
    unsigned short* W1Tl   = (unsigned short*)(wsb + 1835008);
    unsigned short* W2Th   = (unsigned short*)(wsb + 2097152);
    unsigned short* W2Tl   = (unsigned short*)(wsb + 2359296);
    unsigned short* WihH   = (unsigned short*)(wsb + 2621440);   // 768*256*2 = 393216 B
    unsigned short* WihL   = (unsigned short*)(wsb + 3014656);
    unsigned short* WhhH   = (unsigned short*)(wsb + 3407872);
    unsigned short* WhhL   = (unsigned short*)(wsb + 3801088);
    unsigned short* WvTH   = (unsigned short*)(wsb + 4194304);   // 256*128*2 = 65536 B
    unsigned short* WvTl   = (unsigned short*)(wsb + 4259840);
    float* agg_ws = out;   // agg accumulator in d_out (zeroed by K1 chunk0)

    k_prep<<<dim3(592), dim3(256), 0, stream>>>(
        slots, Wq, bq, g_pre, b_pre, Wk, bk, W1, W2, W_ih, W_hh, Wv,
        qkT_ws, qb_ws, W1Th, W1Tl, W2Th, W2Tl,
        WihH, WihL, WhhH, WhhL, WvTH, WvTl, agg_ws);
    k_attn<<<dim3(32, 32), dim3(256), 0, stream>>>(
        features, WvTH, WvTl, bv, qkT_ws, qb_ws, agg_ws);
    k_gate<<<dim3(24, 4), dim3(256), 0, stream>>>(
        agg_ws, slots, WihH, WihL, b_ih, WhhH, WhhL, b_hh, G);
    k_gru2<<<dim3(16), dim3(256), 0, stream>>>(
        slots, G, W1Th, W1Tl, b1, W2Th, W2Tl, b2, g_post, b_post, out);
}